// Round 6
// baseline (435.873 us; speedup 1.0000x reference)
//
#include <hip/hip_runtime.h>
#include <hip/hip_bf16.h>
#include <cstdint>

// B=2, L=2048, D=2048, H=16, HD=128 ; M = B*L = 4096, Nqkv = 6144
typedef short short8 __attribute__((ext_vector_type(8)));
typedef float f32x4 __attribute__((ext_vector_type(4)));
typedef int i32x4 __attribute__((ext_vector_type(4)));

#define AS1 __attribute__((address_space(1)))
#define AS3 __attribute__((address_space(3)))

static __device__ __forceinline__ void async_cp16(const void* g, void* l) {
  __builtin_amdgcn_global_load_lds((const AS1 unsigned int*)g, (AS3 unsigned int*)l, 16, 0, 0);
}

static __device__ __forceinline__ ushort f2bf(float f) {
  unsigned u = __builtin_bit_cast(unsigned, f);
  u += 0x7fffu + ((u >> 16) & 1u);
  return (ushort)(u >> 16);
}
static __device__ __forceinline__ float bf2f(ushort h) {
  unsigned u = ((unsigned)h) << 16;
  return __builtin_bit_cast(float, u);
}

#define FENCE asm volatile("" ::: "memory")
#define BARRIER do { FENCE; __builtin_amdgcn_s_barrier(); FENCE; } while (0)
#define WAITLGKM asm volatile("s_waitcnt lgkmcnt(0)" ::: "memory")
#define WAITVM(N) asm volatile("s_waitcnt vmcnt(" #N ")" ::: "memory")

// ---------------- fp32 -> bf16 convert (x) ----------------
__global__ void cvt_bf16_kernel(const float* __restrict__ in, ushort* __restrict__ out, int n4) {
  int i = blockIdx.x * blockDim.x + threadIdx.x;
  if (i >= n4) return;
  float4 v = ((const float4*)in)[i];
  ushort4 o;
  o.x = f2bf(v.x); o.y = f2bf(v.y); o.z = f2bf(v.z); o.w = f2bf(v.w);
  ((ushort4*)out)[i] = o;
}

// ---------------- fp32 [R][C] -> bf16 [C][R] (weights to B^T layout) ----------------
__global__ void transpose_cvt_kernel(const float* __restrict__ in, ushort* __restrict__ out,
                                     int R, int C) {
  __shared__ ushort tile[32][33];
  int c0 = blockIdx.x * 32, r0 = blockIdx.y * 32;
  int tx = threadIdx.x, ty = threadIdx.y;  // 32 x 8
  for (int j = 0; j < 32; j += 8)
    tile[ty + j][tx] = f2bf(in[(size_t)(r0 + ty + j) * C + c0 + tx]);
  __syncthreads();
  for (int j = 0; j < 32; j += 8)
    out[(size_t)(c0 + ty + j) * R + r0 + tx] = tile[tx][ty + j];
}

// ---------------- QKV GEMM: 256x256 tile, BK=64, 8 waves, 8-phase schedule ----------------
// v2 (depth-4 pipeline): region algebra -- A halves of a buffer are fully read by ph3 of
// its block (quadrant reads span both halves across waves), B halves by ph2. Issues:
// (t+2).B0 @ ph3, (t+2).{B1,A0,A1} @ ph4 (all after last-read barriers). Every half of
// t+1 is issued by the PREVIOUS ph4/ph8, so gates are vmcnt(8) (= t+2's 8 loads
// outstanding) with a 4-phase issue->need distance (~2x the old vmcnt(4) schedule).
// XCD-bijective remap (384 = 8*48): tile-row pairs cluster per XCD -> A panels (2 MB)
// L2-resident.
__global__ __launch_bounds__(512, 2) void gemm_qkv_kernel(
    const ushort* __restrict__ A, const ushort* __restrict__ Bt,
    ushort* __restrict__ qr, ushort* __restrict__ kr, ushort* __restrict__ vt,
    int K, int N) {
  __shared__ __align__(16) ushort smem[65536];  // 128 KiB: [buf][A 16384 | B 16384]
  const int tid = threadIdx.x;
  const int wave = tid >> 6, lane = tid & 63;
  const int wm = wave >> 2, wn = wave & 3;  // 2 (M) x 4 (N) waves; wave tile 128x64
  const int hid = blockIdx.y * 24 + blockIdx.x;       // 0..383
  const int swzg = (hid & 7) * 48 + (hid >> 3);       // XCD-bijective (384 = 8*48)
  const int m0 = (swzg / 24) * 256, n0 = (swzg % 24) * 256;
  const int frl = lane & 15, fq = lane >> 4;
  const int sx = fq ^ (frl & 7);   // ds_read phys slot base (kk adds ^ (kk<<2))
  const int srow = tid >> 3;       // staging row 0..63 within half-tile (j adds 64)
  const int slog8 = (((tid & 7) ^ ((tid >> 3) & 7)) << 3);  // pre-swizzled global col

  const ushort* aG = A + (size_t)(m0 + srow) * K + slog8;
  const ushort* bG = Bt + (size_t)(n0 + srow) * K + slog8;
  ushort* lw = smem + wave * 512;  // wave-uniform LDS staging base

  f32x4 acc[8][4] = {};
  short8 aF[4][2], bF[2][2][2];

  auto stA = [&](int tt, int h) {
    ushort* l = lw + (tt & 1) * 32768 + h * 8192;
    const ushort* g = aG + (size_t)(h * 128) * K + tt * 64;
    async_cp16(g, l);
    async_cp16(g + (size_t)64 * K, l + 4096);
  };
  auto stB = [&](int tt, int h) {
    ushort* l = lw + (tt & 1) * 32768 + 16384 + h * 8192;
    const ushort* g = bG + (size_t)(h * 128) * K + tt * 64;
    async_cp16(g, l);
    async_cp16(g + (size_t)64 * K, l + 4096);
  };
  auto LDA = [&](int buf, int mh) {
#pragma unroll
    for (int mf = 0; mf < 4; ++mf)
#pragma unroll
      for (int kk = 0; kk < 2; ++kk)
        aF[mf][kk] = *(const short8*)(smem + buf * 32768 +
            (wm * 128 + mh * 64 + mf * 16 + frl) * 64 + ((sx ^ (kk << 2)) << 3));
  };
  auto LDB = [&](int buf, int nh) {
#pragma unroll
    for (int j = 0; j < 2; ++j)
#pragma unroll
      for (int kk = 0; kk < 2; ++kk)
        bF[nh][j][kk] = *(const short8*)(smem + buf * 32768 + 16384 +
            (wn * 64 + nh * 32 + j * 16 + frl) * 64 + ((sx ^ (kk << 2)) << 3));
  };
  auto MFMAQ = [&](int mh, int nh) {
    __builtin_amdgcn_s_setprio(1);
#pragma unroll
    for (int mf = 0; mf < 4; ++mf)
#pragma unroll
      for (int j = 0; j < 2; ++j)
#pragma unroll
        for (int kk = 0; kk < 2; ++kk)
          acc[mh * 4 + mf][nh * 2 + j] = __builtin_amdgcn_mfma_f32_16x16x32_bf16(
              aF[mf][kk], bF[nh][j][kk], acc[mh * 4 + mf][nh * 2 + j], 0, 0, 0);
    __builtin_amdgcn_s_setprio(0);
  };

  // prologue: t0 and t1 fully staged; gate leaves t1's 8 loads in flight
  stB(0, 0); stB(0, 1); stA(0, 0); stA(0, 1);
  stB(1, 0); stB(1, 1); stA(1, 0); stA(1, 1);
  WAITVM(8);
  BARRIER;

  const int NT = K >> 6;  // 32 K-steps
  for (int i = 0; i < NT / 2 - 1; ++i) {
    const int t = 2 * i;
    LDA(0, 0); LDB(0, 0);
    BARRIER; WAITLGKM; MFMAQ(0, 0); BARRIER;
    LDB(0, 1);
    BARRIER; WAITLGKM; MFMAQ(0, 1); BARRIER;
    LDA(0, 1); stB(t + 2, 0);
    BARRIER; WAITLGKM; MFMAQ(1, 0); BARRIER;
    stB(t + 2, 1); stA(t + 2, 0); stA(t + 2, 1);
    BARRIER; WAITLGKM; MFMAQ(1, 1); WAITVM(8); BARRIER;
    LDA(1, 0); LDB(1, 0);
    BARRIER; WAITLGKM; MFMAQ(0, 0); BARRIER;
    LDB(1, 1);
    BARRIER; WAITLGKM; MFMAQ(0, 1); BARRIER;
    LDA(1, 1); stB(t + 3, 0);
    BARRIER; WAITLGKM; MFMAQ(1, 0); BARRIER;
    stB(t + 3, 1); stA(t + 3, 0); stA(t + 3, 1);
    BARRIER; WAITLGKM; MFMAQ(1, 1); WAITVM(8); BARRIER;
  }
  {  // peeled final iteration (t = NT-2): no issues; drain before buf1 reads
    LDA(0, 0); LDB(0, 0);
    BARRIER; WAITLGKM; MFMAQ(0, 0); BARRIER;
    LDB(0, 1);
    BARRIER; WAITLGKM; MFMAQ(0, 1); BARRIER;
    LDA(0, 1);
    BARRIER; WAITLGKM; MFMAQ(1, 0); BARRIER;
    BARRIER; WAITLGKM; MFMAQ(1, 1); WAITVM(0); BARRIER;
    LDA(1, 0); LDB(1, 0);
    BARRIER; WAITLGKM; MFMAQ(0, 0); BARRIER;
    LDB(1, 1);
    BARRIER; WAITLGKM; MFMAQ(0, 1); BARRIER;
    LDA(1, 1);
    BARRIER; WAITLGKM; MFMAQ(1, 0); BARRIER;
    BARRIER; WAITLGKM; MFMAQ(1, 1); BARRIER;
  }

  // ---- epilogue: per-wave 128x64 tile at (m0+wm*128, n0+wn*64) ----
  const int rq = fq * 4;
  if (n0 < 4096) {
    ushort* dst = (n0 >= 2048) ? kr : qr;
#pragma unroll
    for (int mi = 0; mi < 8; ++mi)
#pragma unroll
      for (int ni = 0; ni < 4; ++ni) {
        int col = n0 + wn * 64 + ni * 16 + frl;
        int rem = col & 2047, h = rem >> 7, dh = rem & 127;
#pragma unroll
        for (int r = 0; r < 4; ++r) {
          int row = m0 + wm * 128 + mi * 16 + rq + r;
          int b = row >> 11, l = row & 2047;
          dst[((size_t)((b << 4) + h) * 2048 + l) * 128 + dh] = f2bf(acc[mi][ni][r]);
        }
      }
  } else {
    // V: wave-private barrier-free LDS transpose of 16x64 slices (reuses staging smem)
    ushort* vtile = smem + wave * 1024;
    const int col0 = n0 + wn * 64;  // >= 4096
    const int row0 = m0 + wm * 128;
    const int b = row0 >> 11, l0 = row0 & 2047;
    const int swz = (frl & 3) << 4;
#pragma unroll
    for (int hm = 0; hm < 2; ++hm)
#pragma unroll
      for (int ni = 0; ni < 4; ++ni) {
#pragma unroll
        for (int mi = 0; mi < 4; ++mi)
#pragma unroll
          for (int r = 0; r < 4; ++r) {
            int ll = mi * 16 + rq + r;
            vtile[frl * 64 + (ll ^ swz)] = f2bf(acc[hm * 4 + mi][ni][r]);
          }
#pragma unroll
        for (int tt = 0; tt < 2; ++tt) {
          int dl = tt * 8 + (lane >> 3);
          int l8 = (lane & 7) * 8;
          int lsw = l8 ^ ((dl & 3) << 4);
          int rem = (col0 + ni * 16 + dl) & 2047;
          int h = rem >> 7, dh = rem & 127;
          *(short8*)(vt + ((size_t)((b << 4) + h) * 128 + dh) * 2048 + l0 + hm * 64 + l8) =
              *(const short8*)(vtile + dl * 64 + lsw);
        }
      }
  }
}

// ---------------- GEMM -> fp32 out (proj), 128x128 tile (unchanged) ----------------
__global__ __launch_bounds__(256) void gemm_out_kernel(
    const ushort* __restrict__ A, const ushort* __restrict__ Bt,
    float* __restrict__ C, int K, int N) {
  __shared__ __align__(16) ushort As[128 * 32];
  __shared__ __align__(16) ushort Bs[128 * 32];
  const int tid = threadIdx.x;
  const int wave = tid >> 6, lane = tid & 63;
  const int wr = (wave >> 1) * 64, wc = (wave & 1) * 64;
  const int m0 = blockIdx.y * 128, n0 = blockIdx.x * 128;
  const int l4 = lane >> 2, lb8 = (lane & 3) * 8;
  const int fr = lane & 15, fq8 = (lane >> 4) * 8;

  f32x4 acc[4][4] = {};

  for (int k0 = 0; k0 < K; k0 += 32) {
#pragma unroll
    for (int j = 0; j < 2; ++j) {
      const int r = wave * 32 + j * 16 + l4;
      async_cp16(A + (size_t)(m0 + r) * K + k0 + lb8, As + wave * 1024 + j * 512);
      async_cp16(Bt + (size_t)(n0 + r) * K + k0 + lb8, Bs + wave * 1024 + j * 512);
    }
    __syncthreads();
    short8 af[4], bf_[4];
#pragma unroll
    for (int i = 0; i < 4; ++i) {
      af[i] = *(const short8*)(As + (wr + i * 16 + fr) * 32 + fq8);
      bf_[i] = *(const short8*)(Bs + (wc + i * 16 + fr) * 32 + fq8);
    }
#pragma unroll
    for (int mi = 0; mi < 4; ++mi)
#pragma unroll
      for (int ni = 0; ni < 4; ++ni)
        acc[mi][ni] = __builtin_amdgcn_mfma_f32_16x16x32_bf16(af[mi], bf_[ni], acc[mi][ni], 0, 0, 0);
    __syncthreads();
  }

  const int rq = (lane >> 4) * 4;
#pragma unroll
  for (int mi = 0; mi < 4; ++mi)
#pragma unroll
    for (int ni = 0; ni < 4; ++ni) {
      int col = n0 + wc + ni * 16 + fr;
#pragma unroll
      for (int r = 0; r < 4; ++r) {
        int row = m0 + wr + mi * 16 + rq + r;
        C[(size_t)row * N + col] = acc[mi][ni][r];
      }
    }
}

// ---------------- RoPE in-place on q and k: [32][2048][128] bf16 ----------------
__global__ void rope_kernel(ushort* __restrict__ q, ushort* __restrict__ k) {
  int idx = blockIdx.x * 256 + threadIdx.x;  // 32*2048*64 pairs
  int i = idx & 63;
  int l = (idx >> 6) & 2047;
  int bh = idx >> 17;
  float inv = __builtin_amdgcn_exp2f(-(float)i * (13.287712379549449f / 64.0f));
  float f = (float)l * inv;
  float s, c;
  sincosf(f, &s, &c);
  size_t base = ((size_t)bh * 2048 + l) * 128 + 2 * i;
  float q0 = bf2f(q[base]), q1 = bf2f(q[base + 1]);
  q[base] = f2bf(q0 * c - q1 * s);
  q[base + 1] = f2bf(q1 * c + q0 * s);
  float k0 = bf2f(k[base]), k1 = bf2f(k[base + 1]);
  k[base] = f2bf(k0 * c - k1 * s);
  k[base + 1] = f2bf(k1 * c + k0 * s);
}

// ---------------- Flash attention v6.1 (unchanged from R5) ----------------
__global__ __launch_bounds__(512, 4) void flash_kernel(
    const ushort* __restrict__ qr, const ushort* __restrict__ kr,
    const ushort* __restrict__ vtg, ushort* __restrict__ att) {
  __shared__ __align__(16) ushort KV[2][16384];  // [buf][ K 64x128 | V^T 128x64 ]

  const int tid = threadIdx.x;
  const int wave = tid >> 6, lane = tid & 63;
  const int bid = blockIdx.x;
  const int swzb = (bid & 7) * 64 + (bid >> 3);  // XCD-bijective (grid 512 = 8*64)
  const int qt = swzb & 15;
  const int bh = swzb >> 4;
  const int q0 = qt * 128 + wave * 16;
  const size_t bh_base = (size_t)bh * 2048 * 128;

  const int fr = lane & 15, fq = lane >> 4;
  const float cs = 0.08838834764831845f * 1.4426950408889634f;  // scale*log2(e)
  const int kswz = (fr & 7) << 3;

  // staging geometry (per wave, pass i=0,1): one K + one V global_load_lds each
  const int krow0 = wave * 8 + fq;            // K row; +4 per pass
  const int kgc = fr * 8;                     // K col (pre-swizzled at issue)
  const int vrow0 = wave * 16 + (lane >> 3);  // V^T row; +8 per pass
  const int vgc = (lane & 7) * 8;

  auto stage = [&](int kt, int buf) {
#pragma unroll
    for (int i = 0; i < 2; ++i) {
      const int krow = krow0 + i * 4;
      async_cp16(kr + bh_base + (size_t)(kt * 64 + krow) * 128 + (kgc ^ ((krow & 7) << 3)),
                 &KV[buf][(wave * 2 + i) * 512]);
      const int vrow = vrow0 + i * 8;
      async_cp16(vtg + bh_base + (size_t)vrow * 2048 + kt * 64 + (vgc ^ ((vrow & 7) << 3)),
                 &KV[buf][8192 + (wave * 2 + i) * 512]);
    }
  };

  short8 qf[4];
  {
    const ushort* qp = qr + bh_base + (size_t)(q0 + fr) * 128 + fq * 8;
#pragma unroll
    for (int kc = 0; kc < 4; ++kc) qf[kc] = *(const short8*)(qp + kc * 32);
  }

  f32x4 oacc[8];
#pragma unroll
  for (int i = 0; i < 8; ++i) oacc[i] = (f32x4){0.f, 0.f, 0.f, 0.f};
  float l_lane = 0.f;

  const int LA = fr + 32 * (fq & 1);  // src lane for P-exchange (and LA+16)
  const bool hi = fq >= 2;

  stage(0, 0);
  stage(1, 1);
  WAITVM(4);  // t0's 4 landed; t1's 4 in flight
  BARRIER;

#pragma unroll 2
  for (int kt = 0; kt < 32; ++kt) {
    const int bo = (kt & 1) * 16384;
    const ushort* kv = &KV[0][0];

    // ---- S^T = K Q^T (swapped): lane -> P[key=16nt+4fq+r][q=fr] ----
    f32x4 sv[4];
    __builtin_amdgcn_s_setprio(1);
#pragma unroll
    for (int nt = 0; nt < 4; ++nt) {
      f32x4 a = (f32x4){0.f, 0.f, 0.f, 0.f};
#pragma unroll
      for (int kc = 0; kc < 4; ++kc) {
        short8 kf = *(const short8*)(kv + bo + (nt * 16 + fr) * 128 + ((kc * 32 + fq * 8) ^ kswz));
        a = __builtin_amdgcn_mfma_f32_16x16x32_bf16(kf, qf[kc], a, 0, 0, 0);
      }
      sv[nt] = a;
    }
    __builtin_amdgcn_s_setprio(0);

    // ---- in-register softmax: exp2 + pack to bf16 dword pairs ----
    int dA[4], dB[4];
#pragma unroll
    for (int nt = 0; nt < 4; ++nt) {
      float p0 = __builtin_amdgcn_exp2f(sv[nt][0] * cs);
      float p1 = __builtin_amdgcn_exp2f(sv[nt][1] * cs);
      float p2 = __builtin_amdgcn_exp2f(sv[nt][2] * cs);
      float p3 = __builtin_amdgcn_exp2f(sv[nt][3] * cs);
      l_lane += (p0 + p1) + (p2 + p3);
      dA[nt] = (int)f2bf(p0) | ((int)f2bf(p1) << 16);
      dB[nt] = (int)f2bf(p2) | ((int)f2bf(p3) << 16);
    }

    // ---- O += P V : exchange P to A-frag layout (q=fr, k=kc2*32+8fq+j), then MFMA ----
    __builtin_amdgcn_s_setprio(1);
#pragma unroll
    for (int kc2 = 0; kc2 < 2; ++kc2) {
      const int ntE = 2 * kc2, ntO = 2 * kc2 + 1;
      int e0 = __shfl(dA[ntE], LA), e1 = __shfl(dB[ntE], LA);
      int e2 = __shfl(dA[ntE], LA + 16), e3 = __shfl(dB[ntE], LA + 16);
      int o0 = __shfl(dA[ntO], LA), o1 = __shfl(dB[ntO], LA);
      int o2 = __shfl(dA[ntO], LA + 16), o3 = __shfl(dB[ntO], LA + 16);
      i32x4 w = (i32x4){hi ? o0 : e0, hi ? o1 : e1, hi ? o2 : e2, hi ? o3 : e3};
      short8 pa = __builtin_bit_cast(short8, w);
#pragma unroll
      for (int dt = 0; dt < 8; ++dt) {
        short8 vf = *(const short8*)(kv + bo + 8192 + (dt * 16 + fr) * 64 +
                                     ((kc2 * 32 + fq * 8) ^ kswz));
        oacc[dt] = __builtin_amdgcn_mfma_f32_16x16x32_bf16(pa, vf, oacc[dt], 0, 0, 0);
      }
    }
    __builtin_amdgcn_s_setprio(0);

    BARRIER;  // all waves done reading buf (kt&1) before overwrite
    if (kt < 30) {
      stage(kt + 2, kt & 1);
      WAITVM(4);  // t(kt+1)'s 4 landed; t(kt+2)'s 4 in flight
    } else {
      WAITVM(0);  // drain tail
    }
    BARRIER;  // publish t(kt+1)
  }

  // ---- epilogue: l reduce (cross-fq), broadcast per output row, store ----
  l_lane += __shfl_xor(l_lane, 16);
  l_lane += __shfl_xor(l_lane, 32);
  const int b = bh >> 4, h = bh & 15;
#pragma unroll
  for (int r = 0; r < 4; ++r) {
    float inv = 1.0f / __shfl(l_lane, fq * 4 + r);
    size_t row = (size_t)(b * 2048 + q0 + fq * 4 + r) * 2048 + h * 128;
#pragma unroll
    for (int dt = 0; dt < 8; ++dt)
      att[row + dt * 16 + fr] = f2bf(oacc[dt][r] * inv);
  }
}

extern "C" void kernel_launch(void* const* d_in, const int* in_sizes, int n_in,
                              void* d_out, int out_size, void* d_ws, size_t ws_size,
                              hipStream_t stream) {
  const float* x = (const float*)d_in[0];       // [2,2048,2048]
  const float* w_qkv = (const float*)d_in[1];   // [2048,6144]
  const float* w_proj = (const float*)d_in[2];  // [2048,2048]
  float* out = (float*)d_out;                   // [2,2048,2048] fp32

  char* p = (char*)d_ws;
  ushort* xb = (ushort*)p;  p += (size_t)4096 * 2048 * 2;
  ushort* wqt = (ushort*)p; p += (size_t)6144 * 2048 * 2;
  ushort* wpt = (ushort*)p; p += (size_t)2048 * 2048 * 2;
  ushort* qr = (ushort*)p;  p += (size_t)32 * 2048 * 128 * 2;
  ushort* kr = (ushort*)p;  p += (size_t)32 * 2048 * 128 * 2;
  ushort* vt = (ushort*)p;  p += (size_t)32 * 2048 * 128 * 2;  // [bh][128][2048]
  ushort* att = (ushort*)p; p += (size_t)4096 * 2048 * 2;

  cvt_bf16_kernel<<<8192, 256, 0, stream>>>(x, xb, 4096 * 2048 / 4);
  transpose_cvt_kernel<<<dim3(192, 64), dim3(32, 8), 0, stream>>>(w_qkv, wqt, 2048, 6144);
  transpose_cvt_kernel<<<dim3(64, 64), dim3(32, 8), 0, stream>>>(w_proj, wpt, 2048, 2048);
  gemm_qkv_kernel<<<dim3(24, 16), 512, 0, stream>>>(xb, wqt, qr, kr, vt, 2048, 6144);
  rope_kernel<<<16384, 256, 0, stream>>>(qr, kr);
  flash_kernel<<<512, 512, 0, stream>>>(qr, kr, vt, att);
  gemm_out_kernel<<<dim3(16, 32), 256, 0, stream>>>(att, wpt, out, 2048, 2048);
}

// Round 7
// 432.978 us; speedup vs baseline: 1.0067x; 1.0067x over previous
//
#include <hip/hip_runtime.h>
#include <hip/hip_bf16.h>
#include <cstdint>

// B=2, L=2048, D=2048, H=16, HD=128 ; M = B*L = 4096, Nqkv = 6144
typedef short short8 __attribute__((ext_vector_type(8)));
typedef float f32x4 __attribute__((ext_vector_type(4)));
typedef int i32x4 __attribute__((ext_vector_type(4)));

#define AS1 __attribute__((address_space(1)))
#define AS3 __attribute__((address_space(3)))

static __device__ __forceinline__ void async_cp16(const void* g, void* l) {
  __builtin_amdgcn_global_load_lds((const AS1 unsigned int*)g, (AS3 unsigned int*)l, 16, 0, 0);
}

static __device__ __forceinline__ ushort f2bf(float f) {
  unsigned u = __builtin_bit_cast(unsigned, f);
  u += 0x7fffu + ((u >> 16) & 1u);
  return (ushort)(u >> 16);
}
static __device__ __forceinline__ float bf2f(ushort h) {
  unsigned u = ((unsigned)h) << 16;
  return __builtin_bit_cast(float, u);
}

#define FENCE asm volatile("" ::: "memory")
#define BARRIER do { FENCE; __builtin_amdgcn_s_barrier(); FENCE; } while (0)
#define WAITLGKM asm volatile("s_waitcnt lgkmcnt(0)" ::: "memory")
#define WAITVM(N) asm volatile("s_waitcnt vmcnt(" #N ")" ::: "memory")

// ---------------- fp32 -> bf16 convert (x) ----------------
__global__ void cvt_bf16_kernel(const float* __restrict__ in, ushort* __restrict__ out, int n4) {
  int i = blockIdx.x * blockDim.x + threadIdx.x;
  if (i >= n4) return;
  float4 v = ((const float4*)in)[i];
  ushort4 o;
  o.x = f2bf(v.x); o.y = f2bf(v.y); o.z = f2bf(v.z); o.w = f2bf(v.w);
  ((ushort4*)out)[i] = o;
}

// ---------------- fp32 [R][C] -> bf16 [C][R] (weights to B^T layout) ----------------
__global__ void transpose_cvt_kernel(const float* __restrict__ in, ushort* __restrict__ out,
                                     int R, int C) {
  __shared__ ushort tile[32][33];
  int c0 = blockIdx.x * 32, r0 = blockIdx.y * 32;
  int tx = threadIdx.x, ty = threadIdx.y;  // 32 x 8
  for (int j = 0; j < 32; j += 8)
    tile[ty + j][tx] = f2bf(in[(size_t)(r0 + ty + j) * C + c0 + tx]);
  __syncthreads();
  for (int j = 0; j < 32; j += 8)
    out[(size_t)(c0 + ty + j) * R + r0 + tx] = tile[tx][ty + j];
}

// ---------------- QKV GEMM: 256x256 tile, BK=64, 8 waves, 8-phase schedule ----------------
// v3: depth-4 pipeline (vmcnt(8), 4-phase issue->need distance) with the DEFAULT block
// mapping restored. R6 lesson: the tile-row-per-XCD remap made every XCD stream ALL of
// B (FETCH 101->183 MB); default (24,16) dispatch gives each XCD 3 fixed B-column panels
// (3 MB, L2-resident) + streamed A -- already the right locality. Single change vs R6.
__global__ __launch_bounds__(512, 2) void gemm_qkv_kernel(
    const ushort* __restrict__ A, const ushort* __restrict__ Bt,
    ushort* __restrict__ qr, ushort* __restrict__ kr, ushort* __restrict__ vt,
    int K, int N) {
  __shared__ __align__(16) ushort smem[65536];  // 128 KiB: [buf][A 16384 | B 16384]
  const int tid = threadIdx.x;
  const int wave = tid >> 6, lane = tid & 63;
  const int wm = wave >> 2, wn = wave & 3;  // 2 (M) x 4 (N) waves; wave tile 128x64
  const int m0 = blockIdx.y * 256, n0 = blockIdx.x * 256;
  const int frl = lane & 15, fq = lane >> 4;
  const int sx = fq ^ (frl & 7);   // ds_read phys slot base (kk adds ^ (kk<<2))
  const int srow = tid >> 3;       // staging row 0..63 within half-tile (j adds 64)
  const int slog8 = (((tid & 7) ^ ((tid >> 3) & 7)) << 3);  // pre-swizzled global col

  const ushort* aG = A + (size_t)(m0 + srow) * K + slog8;
  const ushort* bG = Bt + (size_t)(n0 + srow) * K + slog8;
  ushort* lw = smem + wave * 512;  // wave-uniform LDS staging base

  f32x4 acc[8][4] = {};
  short8 aF[4][2], bF[2][2][2];

  auto stA = [&](int tt, int h) {
    ushort* l = lw + (tt & 1) * 32768 + h * 8192;
    const ushort* g = aG + (size_t)(h * 128) * K + tt * 64;
    async_cp16(g, l);
    async_cp16(g + (size_t)64 * K, l + 4096);
  };
  auto stB = [&](int tt, int h) {
    ushort* l = lw + (tt & 1) * 32768 + 16384 + h * 8192;
    const ushort* g = bG + (size_t)(h * 128) * K + tt * 64;
    async_cp16(g, l);
    async_cp16(g + (size_t)64 * K, l + 4096);
  };
  auto LDA = [&](int buf, int mh) {
#pragma unroll
    for (int mf = 0; mf < 4; ++mf)
#pragma unroll
      for (int kk = 0; kk < 2; ++kk)
        aF[mf][kk] = *(const short8*)(smem + buf * 32768 +
            (wm * 128 + mh * 64 + mf * 16 + frl) * 64 + ((sx ^ (kk << 2)) << 3));
  };
  auto LDB = [&](int buf, int nh) {
#pragma unroll
    for (int j = 0; j < 2; ++j)
#pragma unroll
      for (int kk = 0; kk < 2; ++kk)
        bF[nh][j][kk] = *(const short8*)(smem + buf * 32768 + 16384 +
            (wn * 64 + nh * 32 + j * 16 + frl) * 64 + ((sx ^ (kk << 2)) << 3));
  };
  auto MFMAQ = [&](int mh, int nh) {
    __builtin_amdgcn_s_setprio(1);
#pragma unroll
    for (int mf = 0; mf < 4; ++mf)
#pragma unroll
      for (int j = 0; j < 2; ++j)
#pragma unroll
        for (int kk = 0; kk < 2; ++kk)
          acc[mh * 4 + mf][nh * 2 + j] = __builtin_amdgcn_mfma_f32_16x16x32_bf16(
              aF[mf][kk], bF[nh][j][kk], acc[mh * 4 + mf][nh * 2 + j], 0, 0, 0);
    __builtin_amdgcn_s_setprio(0);
  };

  // prologue: t0 and t1 fully staged; gate leaves t1's 8 loads in flight
  stB(0, 0); stB(0, 1); stA(0, 0); stA(0, 1);
  stB(1, 0); stB(1, 1); stA(1, 0); stA(1, 1);
  WAITVM(8);
  BARRIER;

  const int NT = K >> 6;  // 32 K-steps
  for (int i = 0; i < NT / 2 - 1; ++i) {
    const int t = 2 * i;
    LDA(0, 0); LDB(0, 0);
    BARRIER; WAITLGKM; MFMAQ(0, 0); BARRIER;
    LDB(0, 1);
    BARRIER; WAITLGKM; MFMAQ(0, 1); BARRIER;
    LDA(0, 1); stB(t + 2, 0);
    BARRIER; WAITLGKM; MFMAQ(1, 0); BARRIER;
    stB(t + 2, 1); stA(t + 2, 0); stA(t + 2, 1);
    BARRIER; WAITLGKM; MFMAQ(1, 1); WAITVM(8); BARRIER;
    LDA(1, 0); LDB(1, 0);
    BARRIER; WAITLGKM; MFMAQ(0, 0); BARRIER;
    LDB(1, 1);
    BARRIER; WAITLGKM; MFMAQ(0, 1); BARRIER;
    LDA(1, 1); stB(t + 3, 0);
    BARRIER; WAITLGKM; MFMAQ(1, 0); BARRIER;
    stB(t + 3, 1); stA(t + 3, 0); stA(t + 3, 1);
    BARRIER; WAITLGKM; MFMAQ(1, 1); WAITVM(8); BARRIER;
  }
  {  // peeled final iteration (t = NT-2): no issues; drain before buf1 reads
    LDA(0, 0); LDB(0, 0);
    BARRIER; WAITLGKM; MFMAQ(0, 0); BARRIER;
    LDB(0, 1);
    BARRIER; WAITLGKM; MFMAQ(0, 1); BARRIER;
    LDA(0, 1);
    BARRIER; WAITLGKM; MFMAQ(1, 0); BARRIER;
    BARRIER; WAITLGKM; MFMAQ(1, 1); WAITVM(0); BARRIER;
    LDA(1, 0); LDB(1, 0);
    BARRIER; WAITLGKM; MFMAQ(0, 0); BARRIER;
    LDB(1, 1);
    BARRIER; WAITLGKM; MFMAQ(0, 1); BARRIER;
    LDA(1, 1);
    BARRIER; WAITLGKM; MFMAQ(1, 0); BARRIER;
    BARRIER; WAITLGKM; MFMAQ(1, 1); BARRIER;
  }

  // ---- epilogue: per-wave 128x64 tile at (m0+wm*128, n0+wn*64) ----
  const int rq = fq * 4;
  if (n0 < 4096) {
    ushort* dst = (n0 >= 2048) ? kr : qr;
#pragma unroll
    for (int mi = 0; mi < 8; ++mi)
#pragma unroll
      for (int ni = 0; ni < 4; ++ni) {
        int col = n0 + wn * 64 + ni * 16 + frl;
        int rem = col & 2047, h = rem >> 7, dh = rem & 127;
#pragma unroll
        for (int r = 0; r < 4; ++r) {
          int row = m0 + wm * 128 + mi * 16 + rq + r;
          int b = row >> 11, l = row & 2047;
          dst[((size_t)((b << 4) + h) * 2048 + l) * 128 + dh] = f2bf(acc[mi][ni][r]);
        }
      }
  } else {
    // V: wave-private barrier-free LDS transpose of 16x64 slices (reuses staging smem)
    ushort* vtile = smem + wave * 1024;
    const int col0 = n0 + wn * 64;  // >= 4096
    const int row0 = m0 + wm * 128;
    const int b = row0 >> 11, l0 = row0 & 2047;
    const int swz = (frl & 3) << 4;
#pragma unroll
    for (int hm = 0; hm < 2; ++hm)
#pragma unroll
      for (int ni = 0; ni < 4; ++ni) {
#pragma unroll
        for (int mi = 0; mi < 4; ++mi)
#pragma unroll
          for (int r = 0; r < 4; ++r) {
            int ll = mi * 16 + rq + r;
            vtile[frl * 64 + (ll ^ swz)] = f2bf(acc[hm * 4 + mi][ni][r]);
          }
#pragma unroll
        for (int tt = 0; tt < 2; ++tt) {
          int dl = tt * 8 + (lane >> 3);
          int l8 = (lane & 7) * 8;
          int lsw = l8 ^ ((dl & 3) << 4);
          int rem = (col0 + ni * 16 + dl) & 2047;
          int h = rem >> 7, dh = rem & 127;
          *(short8*)(vt + ((size_t)((b << 4) + h) * 128 + dh) * 2048 + l0 + hm * 64 + l8) =
              *(const short8*)(vtile + dl * 64 + lsw);
        }
      }
  }
}

// ---------------- GEMM -> fp32 out (proj), 128x128 tile (unchanged) ----------------
__global__ __launch_bounds__(256) void gemm_out_kernel(
    const ushort* __restrict__ A, const ushort* __restrict__ Bt,
    float* __restrict__ C, int K, int N) {
  __shared__ __align__(16) ushort As[128 * 32];
  __shared__ __align__(16) ushort Bs[128 * 32];
  const int tid = threadIdx.x;
  const int wave = tid >> 6, lane = tid & 63;
  const int wr = (wave >> 1) * 64, wc = (wave & 1) * 64;
  const int m0 = blockIdx.y * 128, n0 = blockIdx.x * 128;
  const int l4 = lane >> 2, lb8 = (lane & 3) * 8;
  const int fr = lane & 15, fq8 = (lane >> 4) * 8;

  f32x4 acc[4][4] = {};

  for (int k0 = 0; k0 < K; k0 += 32) {
#pragma unroll
    for (int j = 0; j < 2; ++j) {
      const int r = wave * 32 + j * 16 + l4;
      async_cp16(A + (size_t)(m0 + r) * K + k0 + lb8, As + wave * 1024 + j * 512);
      async_cp16(Bt + (size_t)(n0 + r) * K + k0 + lb8, Bs + wave * 1024 + j * 512);
    }
    __syncthreads();
    short8 af[4], bf_[4];
#pragma unroll
    for (int i = 0; i < 4; ++i) {
      af[i] = *(const short8*)(As + (wr + i * 16 + fr) * 32 + fq8);
      bf_[i] = *(const short8*)(Bs + (wc + i * 16 + fr) * 32 + fq8);
    }
#pragma unroll
    for (int mi = 0; mi < 4; ++mi)
#pragma unroll
      for (int ni = 0; ni < 4; ++ni)
        acc[mi][ni] = __builtin_amdgcn_mfma_f32_16x16x32_bf16(af[mi], bf_[ni], acc[mi][ni], 0, 0, 0);
    __syncthreads();
  }

  const int rq = (lane >> 4) * 4;
#pragma unroll
  for (int mi = 0; mi < 4; ++mi)
#pragma unroll
    for (int ni = 0; ni < 4; ++ni) {
      int col = n0 + wc + ni * 16 + fr;
#pragma unroll
      for (int r = 0; r < 4; ++r) {
        int row = m0 + wr + mi * 16 + rq + r;
        C[(size_t)row * N + col] = acc[mi][ni][r];
      }
    }
}

// ---------------- RoPE in-place on q and k: [32][2048][128] bf16 ----------------
__global__ void rope_kernel(ushort* __restrict__ q, ushort* __restrict__ k) {
  int idx = blockIdx.x * 256 + threadIdx.x;  // 32*2048*64 pairs
  int i = idx & 63;
  int l = (idx >> 6) & 2047;
  int bh = idx >> 17;
  float inv = __builtin_amdgcn_exp2f(-(float)i * (13.287712379549449f / 64.0f));
  float f = (float)l * inv;
  float s, c;
  sincosf(f, &s, &c);
  size_t base = ((size_t)bh * 2048 + l) * 128 + 2 * i;
  float q0 = bf2f(q[base]), q1 = bf2f(q[base + 1]);
  q[base] = f2bf(q0 * c - q1 * s);
  q[base + 1] = f2bf(q1 * c + q0 * s);
  float k0 = bf2f(k[base]), k1 = bf2f(k[base + 1]);
  k[base] = f2bf(k0 * c - k1 * s);
  k[base + 1] = f2bf(k1 * c + k0 * s);
}

// ---------------- Flash attention v6.1 (unchanged from R5) ----------------
__global__ __launch_bounds__(512, 4) void flash_kernel(
    const ushort* __restrict__ qr, const ushort* __restrict__ kr,
    const ushort* __restrict__ vtg, ushort* __restrict__ att) {
  __shared__ __align__(16) ushort KV[2][16384];  // [buf][ K 64x128 | V^T 128x64 ]

  const int tid = threadIdx.x;
  const int wave = tid >> 6, lane = tid & 63;
  const int bid = blockIdx.x;
  const int swzb = (bid & 7) * 64 + (bid >> 3);  // XCD-bijective (grid 512 = 8*64)
  const int qt = swzb & 15;
  const int bh = swzb >> 4;
  const int q0 = qt * 128 + wave * 16;
  const size_t bh_base = (size_t)bh * 2048 * 128;

  const int fr = lane & 15, fq = lane >> 4;
  const float cs = 0.08838834764831845f * 1.4426950408889634f;  // scale*log2(e)
  const int kswz = (fr & 7) << 3;

  // staging geometry (per wave, pass i=0,1): one K + one V global_load_lds each
  const int krow0 = wave * 8 + fq;            // K row; +4 per pass
  const int kgc = fr * 8;                     // K col (pre-swizzled at issue)
  const int vrow0 = wave * 16 + (lane >> 3);  // V^T row; +8 per pass
  const int vgc = (lane & 7) * 8;

  auto stage = [&](int kt, int buf) {
#pragma unroll
    for (int i = 0; i < 2; ++i) {
      const int krow = krow0 + i * 4;
      async_cp16(kr + bh_base + (size_t)(kt * 64 + krow) * 128 + (kgc ^ ((krow & 7) << 3)),
                 &KV[buf][(wave * 2 + i) * 512]);
      const int vrow = vrow0 + i * 8;
      async_cp16(vtg + bh_base + (size_t)vrow * 2048 + kt * 64 + (vgc ^ ((vrow & 7) << 3)),
                 &KV[buf][8192 + (wave * 2 + i) * 512]);
    }
  };

  short8 qf[4];
  {
    const ushort* qp = qr + bh_base + (size_t)(q0 + fr) * 128 + fq * 8;
#pragma unroll
    for (int kc = 0; kc < 4; ++kc) qf[kc] = *(const short8*)(qp + kc * 32);
  }

  f32x4 oacc[8];
#pragma unroll
  for (int i = 0; i < 8; ++i) oacc[i] = (f32x4){0.f, 0.f, 0.f, 0.f};
  float l_lane = 0.f;

  const int LA = fr + 32 * (fq & 1);  // src lane for P-exchange (and LA+16)
  const bool hi = fq >= 2;

  stage(0, 0);
  stage(1, 1);
  WAITVM(4);  // t0's 4 landed; t1's 4 in flight
  BARRIER;

#pragma unroll 2
  for (int kt = 0; kt < 32; ++kt) {
    const int bo = (kt & 1) * 16384;
    const ushort* kv = &KV[0][0];

    // ---- S^T = K Q^T (swapped): lane -> P[key=16nt+4fq+r][q=fr] ----
    f32x4 sv[4];
    __builtin_amdgcn_s_setprio(1);
#pragma unroll
    for (int nt = 0; nt < 4; ++nt) {
      f32x4 a = (f32x4){0.f, 0.f, 0.f, 0.f};
#pragma unroll
      for (int kc = 0; kc < 4; ++kc) {
        short8 kf = *(const short8*)(kv + bo + (nt * 16 + fr) * 128 + ((kc * 32 + fq * 8) ^ kswz));
        a = __builtin_amdgcn_mfma_f32_16x16x32_bf16(kf, qf[kc], a, 0, 0, 0);
      }
      sv[nt] = a;
    }
    __builtin_amdgcn_s_setprio(0);

    // ---- in-register softmax: exp2 + pack to bf16 dword pairs ----
    int dA[4], dB[4];
#pragma unroll
    for (int nt = 0; nt < 4; ++nt) {
      float p0 = __builtin_amdgcn_exp2f(sv[nt][0] * cs);
      float p1 = __builtin_amdgcn_exp2f(sv[nt][1] * cs);
      float p2 = __builtin_amdgcn_exp2f(sv[nt][2] * cs);
      float p3 = __builtin_amdgcn_exp2f(sv[nt][3] * cs);
      l_lane += (p0 + p1) + (p2 + p3);
      dA[nt] = (int)f2bf(p0) | ((int)f2bf(p1) << 16);
      dB[nt] = (int)f2bf(p2) | ((int)f2bf(p3) << 16);
    }

    // ---- O += P V : exchange P to A-frag layout (q=fr, k=kc2*32+8fq+j), then MFMA ----
    __builtin_amdgcn_s_setprio(1);
#pragma unroll
    for (int kc2 = 0; kc2 < 2; ++kc2) {
      const int ntE = 2 * kc2, ntO = 2 * kc2 + 1;
      int e0 = __shfl(dA[ntE], LA), e1 = __shfl(dB[ntE], LA);
      int e2 = __shfl(dA[ntE], LA + 16), e3 = __shfl(dB[ntE], LA + 16);
      int o0 = __shfl(dA[ntO], LA), o1 = __shfl(dB[ntO], LA);
      int o2 = __shfl(dA[ntO], LA + 16), o3 = __shfl(dB[ntO], LA + 16);
      i32x4 w = (i32x4){hi ? o0 : e0, hi ? o1 : e1, hi ? o2 : e2, hi ? o3 : e3};
      short8 pa = __builtin_bit_cast(short8, w);
#pragma unroll
      for (int dt = 0; dt < 8; ++dt) {
        short8 vf = *(const short8*)(kv + bo + 8192 + (dt * 16 + fr) * 64 +
                                     ((kc2 * 32 + fq * 8) ^ kswz));
        oacc[dt] = __builtin_amdgcn_mfma_f32_16x16x32_bf16(pa, vf, oacc[dt], 0, 0, 0);
      }
    }
    __builtin_amdgcn_s_setprio(0);

    BARRIER;  // all waves done reading buf (kt&1) before overwrite
    if (kt < 30) {
      stage(kt + 2, kt & 1);
      WAITVM(4);  // t(kt+1)'s 4 landed; t(kt+2)'s 4 in flight
    } else {
      WAITVM(0);  // drain tail
    }
    BARRIER;  // publish t(kt+1)
  }

  // ---- epilogue: l reduce (cross-fq), broadcast per output row, store ----
  l_lane += __shfl_xor(l_lane, 16);
  l_lane += __shfl_xor(l_lane, 32);
  const int b = bh >> 4, h = bh & 15;
#pragma unroll
  for (int r = 0; r < 4; ++r) {
    float inv = 1.0f / __shfl(l_lane, fq * 4 + r);
    size_t row = (size_t)(b * 2048 + q0 + fq * 4 + r) * 2048 + h * 128;
#pragma unroll
    for (int dt = 0; dt < 8; ++dt)
      att[row + dt * 16 + fr] = f2bf(oacc[dt][r] * inv);
  }
}

extern "C" void kernel_launch(void* const* d_in, const int* in_sizes, int n_in,
                              void* d_out, int out_size, void* d_ws, size_t ws_size,
                              hipStream_t stream) {
  const float* x = (const float*)d_in[0];       // [2,2048,2048]
  const float* w_qkv = (const float*)d_in[1];   // [2048,6144]
  const float* w_proj = (const float*)d_in[2];  // [2048,2048]
  float* out = (float*)d_out;                   // [2,2048,2048] fp32

  char* p = (char*)d_ws;
  ushort* xb = (ushort*)p;  p += (size_t)4096 * 2048 * 2;
  ushort* wqt = (ushort*)p; p += (size_t)6144 * 2048 * 2;
  ushort* wpt = (ushort*)p; p += (size_t)2048 * 2048 * 2;
  ushort* qr = (ushort*)p;  p += (size_t)32 * 2048 * 128 * 2;
  ushort* kr = (ushort*)p;  p += (size_t)32 * 2048 * 128 * 2;
  ushort* vt = (ushort*)p;  p += (size_t)32 * 2048 * 128 * 2;  // [bh][128][2048]
  ushort* att = (ushort*)p; p += (size_t)4096 * 2048 * 2;

  cvt_bf16_kernel<<<8192, 256, 0, stream>>>(x, xb, 4096 * 2048 / 4);
  transpose_cvt_kernel<<<dim3(192, 64), dim3(32, 8), 0, stream>>>(w_qkv, wqt, 2048, 6144);
  transpose_cvt_kernel<<<dim3(64, 64), dim3(32, 8), 0, stream>>>(w_proj, wpt, 2048, 2048);
  gemm_qkv_kernel<<<dim3(24, 16), 512, 0, stream>>>(xb, wqt, qr, kr, vt, 2048, 6144);
  rope_kernel<<<16384, 256, 0, stream>>>(qr, kr);
  flash_kernel<<<512, 512, 0, stream>>>(qr, kr, vt, att);
  gemm_out_kernel<<<dim3(16, 32), 256, 0, stream>>>(att, wpt, out, 2048, 2048);
}

// Round 8
// 420.937 us; speedup vs baseline: 1.0355x; 1.0286x over previous
//
#include <hip/hip_runtime.h>
#include <hip/hip_bf16.h>
#include <cstdint>

// B=2, L=2048, D=2048, H=16, HD=128 ; M = B*L = 4096, Nqkv = 6144
typedef short short8 __attribute__((ext_vector_type(8)));
typedef float f32x4 __attribute__((ext_vector_type(4)));
typedef int i32x4 __attribute__((ext_vector_type(4)));

#define AS1 __attribute__((address_space(1)))
#define AS3 __attribute__((address_space(3)))

static __device__ __forceinline__ void async_cp16(const void* g, void* l) {
  __builtin_amdgcn_global_load_lds((const AS1 unsigned int*)g, (AS3 unsigned int*)l, 16, 0, 0);
}

static __device__ __forceinline__ ushort f2bf(float f) {
  unsigned u = __builtin_bit_cast(unsigned, f);
  u += 0x7fffu + ((u >> 16) & 1u);
  return (ushort)(u >> 16);
}
static __device__ __forceinline__ float bf2f(ushort h) {
  unsigned u = ((unsigned)h) << 16;
  return __builtin_bit_cast(float, u);
}

#define FENCE asm volatile("" ::: "memory")
#define BARRIER do { FENCE; __builtin_amdgcn_s_barrier(); FENCE; } while (0)
#define WAITLGKM asm volatile("s_waitcnt lgkmcnt(0)" ::: "memory")
#define WAITVM(N) asm volatile("s_waitcnt vmcnt(" #N ")" ::: "memory")

// ---------------- fp32 -> bf16 convert (x) ----------------
__global__ void cvt_bf16_kernel(const float* __restrict__ in, ushort* __restrict__ out, int n4) {
  int i = blockIdx.x * blockDim.x + threadIdx.x;
  if (i >= n4) return;
  float4 v = ((const float4*)in)[i];
  ushort4 o;
  o.x = f2bf(v.x); o.y = f2bf(v.y); o.z = f2bf(v.z); o.w = f2bf(v.w);
  ((ushort4*)out)[i] = o;
}

// ---------------- fp32 [R][C] -> bf16 [C][R] (weights to B^T layout) ----------------
__global__ void transpose_cvt_kernel(const float* __restrict__ in, ushort* __restrict__ out,
                                     int R, int C) {
  __shared__ ushort tile[32][33];
  int c0 = blockIdx.x * 32, r0 = blockIdx.y * 32;
  int tx = threadIdx.x, ty = threadIdx.y;  // 32 x 8
  for (int j = 0; j < 32; j += 8)
    tile[ty + j][tx] = f2bf(in[(size_t)(r0 + ty + j) * C + c0 + tx]);
  __syncthreads();
  for (int j = 0; j < 32; j += 8)
    out[(size_t)(c0 + ty + j) * R + r0 + tx] = tile[tx][ty + j];
}

// ---------------- RoPE cos/sin table: [2048 l][64 i] float2 ----------------
__global__ void rope_tab_kernel(float2* __restrict__ tab) {
  int idx = blockIdx.x * 256 + threadIdx.x;  // 2048*64
  int i = idx & 63, l = idx >> 6;
  float inv = __builtin_amdgcn_exp2f(-(float)i * (13.287712379549449f / 64.0f));
  float f = (float)l * inv;
  float s, c;
  sincosf(f, &s, &c);
  tab[idx] = make_float2(c, s);
}

// ---------------- QKV GEMM: 256x256 tile, BK=64, 8 waves, 8-phase (R5 schedule) -----------
// R7 A/B concluded: depth-4 vmcnt(8) is neutral-to-negative vs R5's vmcnt(4); default
// block mapping already gives each XCD 3 L2-resident B-panels. This is the R5 schedule
// restored, with RoPE FUSED into the q/k epilogue: partner element dh^1 lives at lane^1
// (same mi,ni,r) -> __shfl_xor(v,1); angle from the 1 MB L2-resident table.
__global__ __launch_bounds__(512, 2) void gemm_qkv_kernel(
    const ushort* __restrict__ A, const ushort* __restrict__ Bt,
    ushort* __restrict__ qr, ushort* __restrict__ kr, ushort* __restrict__ vt,
    const float2* __restrict__ rtab, int K, int N) {
  __shared__ __align__(16) ushort smem[65536];  // 128 KiB: [buf][A 16384 | B 16384]
  const int tid = threadIdx.x;
  const int wave = tid >> 6, lane = tid & 63;
  const int wm = wave >> 2, wn = wave & 3;  // 2 (M) x 4 (N) waves; wave tile 128x64
  const int m0 = blockIdx.y * 256, n0 = blockIdx.x * 256;
  const int frl = lane & 15, fq = lane >> 4;
  const int sx = fq ^ (frl & 7);   // ds_read phys slot base (kk adds ^ (kk<<2))
  const int srow = tid >> 3;       // staging row 0..63 within half-tile (j adds 64)
  const int slog8 = (((tid & 7) ^ ((tid >> 3) & 7)) << 3);  // pre-swizzled global col

  const ushort* aG = A + (size_t)(m0 + srow) * K + slog8;
  const ushort* bG = Bt + (size_t)(n0 + srow) * K + slog8;
  ushort* lw = smem + wave * 512;  // wave-uniform LDS staging base

  f32x4 acc[8][4] = {};
  short8 aF[4][2], bF[2][2][2];

  auto stA = [&](int tt, int h) {
    ushort* l = lw + (tt & 1) * 32768 + h * 8192;
    const ushort* g = aG + (size_t)(h * 128) * K + tt * 64;
    async_cp16(g, l);
    async_cp16(g + (size_t)64 * K, l + 4096);
  };
  auto stB = [&](int tt, int h) {
    ushort* l = lw + (tt & 1) * 32768 + 16384 + h * 8192;
    const ushort* g = bG + (size_t)(h * 128) * K + tt * 64;
    async_cp16(g, l);
    async_cp16(g + (size_t)64 * K, l + 4096);
  };
  auto LDA = [&](int buf, int mh) {
#pragma unroll
    for (int mf = 0; mf < 4; ++mf)
#pragma unroll
      for (int kk = 0; kk < 2; ++kk)
        aF[mf][kk] = *(const short8*)(smem + buf * 32768 +
            (wm * 128 + mh * 64 + mf * 16 + frl) * 64 + ((sx ^ (kk << 2)) << 3));
  };
  auto LDB = [&](int buf, int nh) {
#pragma unroll
    for (int j = 0; j < 2; ++j)
#pragma unroll
      for (int kk = 0; kk < 2; ++kk)
        bF[nh][j][kk] = *(const short8*)(smem + buf * 32768 + 16384 +
            (wn * 64 + nh * 32 + j * 16 + frl) * 64 + ((sx ^ (kk << 2)) << 3));
  };
  auto MFMAQ = [&](int mh, int nh) {
    __builtin_amdgcn_s_setprio(1);
#pragma unroll
    for (int mf = 0; mf < 4; ++mf)
#pragma unroll
      for (int j = 0; j < 2; ++j)
#pragma unroll
        for (int kk = 0; kk < 2; ++kk)
          acc[mh * 4 + mf][nh * 2 + j] = __builtin_amdgcn_mfma_f32_16x16x32_bf16(
              aF[mf][kk], bF[nh][j][kk], acc[mh * 4 + mf][nh * 2 + j], 0, 0, 0);
    __builtin_amdgcn_s_setprio(0);
  };

  // prologue: t0 fully, t1.B halves; wait t0 landed (4 newest = t1.B in flight)
  stB(0, 0); stB(0, 1); stA(0, 0); stA(0, 1);
  stB(1, 0); stB(1, 1);
  WAITVM(4);
  BARRIER;

  const int NT = K >> 6;  // 32 K-steps
  for (int i = 0; i < NT / 2 - 1; ++i) {
    const int t = 2 * i;
    LDA(0, 0); LDB(0, 0); stA(t + 1, 0);
    BARRIER; WAITLGKM; MFMAQ(0, 0); BARRIER;
    LDB(0, 1); stA(t + 1, 1);
    BARRIER; WAITLGKM; MFMAQ(0, 1); BARRIER;
    LDA(0, 1); stB(t + 2, 0);
    BARRIER; WAITLGKM; MFMAQ(1, 0); BARRIER;
    stB(t + 2, 1);
    BARRIER; WAITLGKM; MFMAQ(1, 1); WAITVM(4); BARRIER;
    LDA(1, 0); LDB(1, 0); stA(t + 2, 0);
    BARRIER; WAITLGKM; MFMAQ(0, 0); BARRIER;
    LDB(1, 1); stA(t + 2, 1);
    BARRIER; WAITLGKM; MFMAQ(0, 1); BARRIER;
    LDA(1, 1); stB(t + 3, 0);
    BARRIER; WAITLGKM; MFMAQ(1, 0); BARRIER;
    stB(t + 3, 1);
    BARRIER; WAITLGKM; MFMAQ(1, 1); WAITVM(4); BARRIER;
  }
  {  // peeled final iteration (t = NT-2): no t+2/t+3 issues; drain before buf1 reads
    const int t = NT - 2;
    LDA(0, 0); LDB(0, 0); stA(t + 1, 0);
    BARRIER; WAITLGKM; MFMAQ(0, 0); BARRIER;
    LDB(0, 1); stA(t + 1, 1);
    BARRIER; WAITLGKM; MFMAQ(0, 1); BARRIER;
    LDA(0, 1);
    BARRIER; WAITLGKM; MFMAQ(1, 0); BARRIER;
    BARRIER; WAITLGKM; MFMAQ(1, 1); WAITVM(0); BARRIER;
    LDA(1, 0); LDB(1, 0);
    BARRIER; WAITLGKM; MFMAQ(0, 0); BARRIER;
    LDB(1, 1);
    BARRIER; WAITLGKM; MFMAQ(0, 1); BARRIER;
    LDA(1, 1);
    BARRIER; WAITLGKM; MFMAQ(1, 0); BARRIER;
    BARRIER; WAITLGKM; MFMAQ(1, 1); BARRIER;
  }

  // ---- epilogue: per-wave 128x64 tile at (m0+wm*128, n0+wn*64) ----
  const int rq = fq * 4;
  if (n0 < 4096) {
    // q/k with FUSED RoPE: out2i = x1*c - x2*s ; out2i+1 = x2*c + x1*s.
    // Partner element (dh^1) = same (mi,ni,r) at lane^1 (col = ...+frl, parity in frl).
    ushort* dst = (n0 >= 2048) ? kr : qr;
#pragma unroll
    for (int mi = 0; mi < 8; ++mi)
#pragma unroll
      for (int ni = 0; ni < 4; ++ni) {
        int col = n0 + wn * 64 + ni * 16 + frl;
        int rem = col & 2047, h = rem >> 7, dh = rem & 127;
        int ip = dh >> 1;
        float sgn = (dh & 1) ? 1.0f : -1.0f;
#pragma unroll
        for (int r = 0; r < 4; ++r) {
          int row = m0 + wm * 128 + mi * 16 + rq + r;
          int b = row >> 11, l = row & 2047;
          float v = acc[mi][ni][r];
          float vp = __shfl_xor(v, 1);
          float2 cs2 = rtab[l * 64 + ip];
          float o = v * cs2.x + sgn * vp * cs2.y;
          dst[((size_t)((b << 4) + h) * 2048 + l) * 128 + dh] = f2bf(o);
        }
      }
  } else {
    // V: wave-private barrier-free LDS transpose of 16x64 slices (reuses staging smem)
    ushort* vtile = smem + wave * 1024;
    const int col0 = n0 + wn * 64;  // >= 4096
    const int row0 = m0 + wm * 128;
    const int b = row0 >> 11, l0 = row0 & 2047;
    const int swz = (frl & 3) << 4;
#pragma unroll
    for (int hm = 0; hm < 2; ++hm)
#pragma unroll
      for (int ni = 0; ni < 4; ++ni) {
#pragma unroll
        for (int mi = 0; mi < 4; ++mi)
#pragma unroll
          for (int r = 0; r < 4; ++r) {
            int ll = mi * 16 + rq + r;
            vtile[frl * 64 + (ll ^ swz)] = f2bf(acc[hm * 4 + mi][ni][r]);
          }
#pragma unroll
        for (int tt = 0; tt < 2; ++tt) {
          int dl = tt * 8 + (lane >> 3);
          int l8 = (lane & 7) * 8;
          int lsw = l8 ^ ((dl & 3) << 4);
          int rem = (col0 + ni * 16 + dl) & 2047;
          int h = rem >> 7, dh = rem & 127;
          *(short8*)(vt + ((size_t)((b << 4) + h) * 128 + dh) * 2048 + l0 + hm * 64 + l8) =
              *(const short8*)(vtile + dl * 64 + lsw);
        }
      }
  }
}

// ---------------- GEMM -> fp32 out (proj), 128x128 tile (unchanged) ----------------
__global__ __launch_bounds__(256) void gemm_out_kernel(
    const ushort* __restrict__ A, const ushort* __restrict__ Bt,
    float* __restrict__ C, int K, int N) {
  __shared__ __align__(16) ushort As[128 * 32];
  __shared__ __align__(16) ushort Bs[128 * 32];
  const int tid = threadIdx.x;
  const int wave = tid >> 6, lane = tid & 63;
  const int wr = (wave >> 1) * 64, wc = (wave & 1) * 64;
  const int m0 = blockIdx.y * 128, n0 = blockIdx.x * 128;
  const int l4 = lane >> 2, lb8 = (lane & 3) * 8;
  const int fr = lane & 15, fq8 = (lane >> 4) * 8;

  f32x4 acc[4][4] = {};

  for (int k0 = 0; k0 < K; k0 += 32) {
#pragma unroll
    for (int j = 0; j < 2; ++j) {
      const int r = wave * 32 + j * 16 + l4;
      async_cp16(A + (size_t)(m0 + r) * K + k0 + lb8, As + wave * 1024 + j * 512);
      async_cp16(Bt + (size_t)(n0 + r) * K + k0 + lb8, Bs + wave * 1024 + j * 512);
    }
    __syncthreads();
    short8 af[4], bf_[4];
#pragma unroll
    for (int i = 0; i < 4; ++i) {
      af[i] = *(const short8*)(As + (wr + i * 16 + fr) * 32 + fq8);
      bf_[i] = *(const short8*)(Bs + (wc + i * 16 + fr) * 32 + fq8);
    }
#pragma unroll
    for (int mi = 0; mi < 4; ++mi)
#pragma unroll
      for (int ni = 0; ni < 4; ++ni)
        acc[mi][ni] = __builtin_amdgcn_mfma_f32_16x16x32_bf16(af[mi], bf_[ni], acc[mi][ni], 0, 0, 0);
    __syncthreads();
  }

  const int rq = (lane >> 4) * 4;
#pragma unroll
  for (int mi = 0; mi < 4; ++mi)
#pragma unroll
    for (int ni = 0; ni < 4; ++ni) {
      int col = n0 + wc + ni * 16 + fr;
#pragma unroll
      for (int r = 0; r < 4; ++r) {
        int row = m0 + wr + mi * 16 + rq + r;
        C[(size_t)row * N + col] = acc[mi][ni][r];
      }
    }
}

// ---------------- Flash attention v6.1 (unchanged from R5) ----------------
__global__ __launch_bounds__(512, 4) void flash_kernel(
    const ushort* __restrict__ qr, const ushort* __restrict__ kr,
    const ushort* __restrict__ vtg, ushort* __restrict__ att) {
  __shared__ __align__(16) ushort KV[2][16384];  // [buf][ K 64x128 | V^T 128x64 ]

  const int tid = threadIdx.x;
  const int wave = tid >> 6, lane = tid & 63;
  const int bid = blockIdx.x;
  const int swzb = (bid & 7) * 64 + (bid >> 3);  // XCD-bijective (grid 512 = 8*64)
  const int qt = swzb & 15;
  const int bh = swzb >> 4;
  const int q0 = qt * 128 + wave * 16;
  const size_t bh_base = (size_t)bh * 2048 * 128;

  const int fr = lane & 15, fq = lane >> 4;
  const float cs = 0.08838834764831845f * 1.4426950408889634f;  // scale*log2(e)
  const int kswz = (fr & 7) << 3;

  // staging geometry (per wave, pass i=0,1): one K + one V global_load_lds each
  const int krow0 = wave * 8 + fq;            // K row; +4 per pass
  const int kgc = fr * 8;                     // K col (pre-swizzled at issue)
  const int vrow0 = wave * 16 + (lane >> 3);  // V^T row; +8 per pass
  const int vgc = (lane & 7) * 8;

  auto stage = [&](int kt, int buf) {
#pragma unroll
    for (int i = 0; i < 2; ++i) {
      const int krow = krow0 + i * 4;
      async_cp16(kr + bh_base + (size_t)(kt * 64 + krow) * 128 + (kgc ^ ((krow & 7) << 3)),
                 &KV[buf][(wave * 2 + i) * 512]);
      const int vrow = vrow0 + i * 8;
      async_cp16(vtg + bh_base + (size_t)vrow * 2048 + kt * 64 + (vgc ^ ((vrow & 7) << 3)),
                 &KV[buf][8192 + (wave * 2 + i) * 512]);
    }
  };

  short8 qf[4];
  {
    const ushort* qp = qr + bh_base + (size_t)(q0 + fr) * 128 + fq * 8;
#pragma unroll
    for (int kc = 0; kc < 4; ++kc) qf[kc] = *(const short8*)(qp + kc * 32);
  }

  f32x4 oacc[8];
#pragma unroll
  for (int i = 0; i < 8; ++i) oacc[i] = (f32x4){0.f, 0.f, 0.f, 0.f};
  float l_lane = 0.f;

  const int LA = fr + 32 * (fq & 1);  // src lane for P-exchange (and LA+16)
  const bool hi = fq >= 2;

  stage(0, 0);
  stage(1, 1);
  WAITVM(4);  // t0's 4 landed; t1's 4 in flight
  BARRIER;

#pragma unroll 2
  for (int kt = 0; kt < 32; ++kt) {
    const int bo = (kt & 1) * 16384;
    const ushort* kv = &KV[0][0];

    // ---- S^T = K Q^T (swapped): lane -> P[key=16nt+4fq+r][q=fr] ----
    f32x4 sv[4];
    __builtin_amdgcn_s_setprio(1);
#pragma unroll
    for (int nt = 0; nt < 4; ++nt) {
      f32x4 a = (f32x4){0.f, 0.f, 0.f, 0.f};
#pragma unroll
      for (int kc = 0; kc < 4; ++kc) {
        short8 kf = *(const short8*)(kv + bo + (nt * 16 + fr) * 128 + ((kc * 32 + fq * 8) ^ kswz));
        a = __builtin_amdgcn_mfma_f32_16x16x32_bf16(kf, qf[kc], a, 0, 0, 0);
      }
      sv[nt] = a;
    }
    __builtin_amdgcn_s_setprio(0);

    // ---- in-register softmax: exp2 + pack to bf16 dword pairs ----
    int dA[4], dB[4];
#pragma unroll
    for (int nt = 0; nt < 4; ++nt) {
      float p0 = __builtin_amdgcn_exp2f(sv[nt][0] * cs);
      float p1 = __builtin_amdgcn_exp2f(sv[nt][1] * cs);
      float p2 = __builtin_amdgcn_exp2f(sv[nt][2] * cs);
      float p3 = __builtin_amdgcn_exp2f(sv[nt][3] * cs);
      l_lane += (p0 + p1) + (p2 + p3);
      dA[nt] = (int)f2bf(p0) | ((int)f2bf(p1) << 16);
      dB[nt] = (int)f2bf(p2) | ((int)f2bf(p3) << 16);
    }

    // ---- O += P V : exchange P to A-frag layout (q=fr, k=kc2*32+8fq+j), then MFMA ----
    __builtin_amdgcn_s_setprio(1);
#pragma unroll
    for (int kc2 = 0; kc2 < 2; ++kc2) {
      const int ntE = 2 * kc2, ntO = 2 * kc2 + 1;
      int e0 = __shfl(dA[ntE], LA), e1 = __shfl(dB[ntE], LA);
      int e2 = __shfl(dA[ntE], LA + 16), e3 = __shfl(dB[ntE], LA + 16);
      int o0 = __shfl(dA[ntO], LA), o1 = __shfl(dB[ntO], LA);
      int o2 = __shfl(dA[ntO], LA + 16), o3 = __shfl(dB[ntO], LA + 16);
      i32x4 w = (i32x4){hi ? o0 : e0, hi ? o1 : e1, hi ? o2 : e2, hi ? o3 : e3};
      short8 pa = __builtin_bit_cast(short8, w);
#pragma unroll
      for (int dt = 0; dt < 8; ++dt) {
        short8 vf = *(const short8*)(kv + bo + 8192 + (dt * 16 + fr) * 64 +
                                     ((kc2 * 32 + fq * 8) ^ kswz));
        oacc[dt] = __builtin_amdgcn_mfma_f32_16x16x32_bf16(pa, vf, oacc[dt], 0, 0, 0);
      }
    }
    __builtin_amdgcn_s_setprio(0);

    BARRIER;  // all waves done reading buf (kt&1) before overwrite
    if (kt < 30) {
      stage(kt + 2, kt & 1);
      WAITVM(4);  // t(kt+1)'s 4 landed; t(kt+2)'s 4 in flight
    } else {
      WAITVM(0);  // drain tail
    }
    BARRIER;  // publish t(kt+1)
  }

  // ---- epilogue: l reduce (cross-fq), broadcast per output row, store ----
  l_lane += __shfl_xor(l_lane, 16);
  l_lane += __shfl_xor(l_lane, 32);
  const int b = bh >> 4, h = bh & 15;
#pragma unroll
  for (int r = 0; r < 4; ++r) {
    float inv = 1.0f / __shfl(l_lane, fq * 4 + r);
    size_t row = (size_t)(b * 2048 + q0 + fq * 4 + r) * 2048 + h * 128;
#pragma unroll
    for (int dt = 0; dt < 8; ++dt)
      att[row + dt * 16 + fr] = f2bf(oacc[dt][r] * inv);
  }
}

extern "C" void kernel_launch(void* const* d_in, const int* in_sizes, int n_in,
                              void* d_out, int out_size, void* d_ws, size_t ws_size,
                              hipStream_t stream) {
  const float* x = (const float*)d_in[0];       // [2,2048,2048]
  const float* w_qkv = (const float*)d_in[1];   // [2048,6144]
  const float* w_proj = (const float*)d_in[2];  // [2048,2048]
  float* out = (float*)d_out;                   // [2,2048,2048] fp32

  char* p = (char*)d_ws;
  ushort* xb = (ushort*)p;  p += (size_t)4096 * 2048 * 2;
  ushort* wqt = (ushort*)p; p += (size_t)6144 * 2048 * 2;
  ushort* wpt = (ushort*)p; p += (size_t)2048 * 2048 * 2;
  ushort* qr = (ushort*)p;  p += (size_t)32 * 2048 * 128 * 2;
  ushort* kr = (ushort*)p;  p += (size_t)32 * 2048 * 128 * 2;
  ushort* vt = (ushort*)p;  p += (size_t)32 * 2048 * 128 * 2;  // [bh][128][2048]
  ushort* att = (ushort*)p; p += (size_t)4096 * 2048 * 2;
  float2* rtab = (float2*)p; p += (size_t)2048 * 64 * 8;       // 1 MB cos/sin table

  rope_tab_kernel<<<512, 256, 0, stream>>>(rtab);
  cvt_bf16_kernel<<<8192, 256, 0, stream>>>(x, xb, 4096 * 2048 / 4);
  transpose_cvt_kernel<<<dim3(192, 64), dim3(32, 8), 0, stream>>>(w_qkv, wqt, 2048, 6144);
  transpose_cvt_kernel<<<dim3(64, 64), dim3(32, 8), 0, stream>>>(w_proj, wpt, 2048, 2048);
  gemm_qkv_kernel<<<dim3(24, 16), 512, 0, stream>>>(xb, wqt, qr, kr, vt, rtab, 2048, 6144);
  flash_kernel<<<512, 512, 0, stream>>>(qr, kr, vt, att);
  gemm_out_kernel<<<dim3(16, 32), 256, 0, stream>>>(att, wpt, out, 2048, 2048);
}

// Round 10
// 403.475 us; speedup vs baseline: 1.0803x; 1.0433x over previous
//
#include <hip/hip_runtime.h>
#include <hip/hip_bf16.h>
#include <cstdint>

// B=2, L=2048, D=2048, H=16, HD=128 ; M = B*L = 4096, Nqkv = 6144
typedef short short8 __attribute__((ext_vector_type(8)));
typedef float f32x4 __attribute__((ext_vector_type(4)));
typedef float f32x16 __attribute__((ext_vector_type(16)));
typedef int i32x4 __attribute__((ext_vector_type(4)));

#define AS1 __attribute__((address_space(1)))
#define AS3 __attribute__((address_space(3)))

static __device__ __forceinline__ void async_cp16(const void* g, void* l) {
  __builtin_amdgcn_global_load_lds((const AS1 unsigned int*)g, (AS3 unsigned int*)l, 16, 0, 0);
}

static __device__ __forceinline__ ushort f2bf(float f) {
  unsigned u = __builtin_bit_cast(unsigned, f);
  u += 0x7fffu + ((u >> 16) & 1u);
  return (ushort)(u >> 16);
}
static __device__ __forceinline__ float bf2f(ushort h) {
  unsigned u = ((unsigned)h) << 16;
  return __builtin_bit_cast(float, u);
}

#define FENCE asm volatile("" ::: "memory")
#define BARRIER do { FENCE; __builtin_amdgcn_s_barrier(); FENCE; } while (0)
#define WAITLGKM asm volatile("s_waitcnt lgkmcnt(0)" ::: "memory")
#define WAITVM(N) asm volatile("s_waitcnt vmcnt(" #N ")" ::: "memory")

// ---------------- fp32 -> bf16 convert (x) ----------------
__global__ void cvt_bf16_kernel(const float* __restrict__ in, ushort* __restrict__ out, int n4) {
  int i = blockIdx.x * blockDim.x + threadIdx.x;
  if (i >= n4) return;
  float4 v = ((const float4*)in)[i];
  ushort4 o;
  o.x = f2bf(v.x); o.y = f2bf(v.y); o.z = f2bf(v.z); o.w = f2bf(v.w);
  ((ushort4*)out)[i] = o;
}

// ---------------- fp32 [R][C] -> bf16 [C][R] (weights to B^T layout) ----------------
__global__ void transpose_cvt_kernel(const float* __restrict__ in, ushort* __restrict__ out,
                                     int R, int C) {
  __shared__ ushort tile[32][33];
  int c0 = blockIdx.x * 32, r0 = blockIdx.y * 32;
  int tx = threadIdx.x, ty = threadIdx.y;  // 32 x 8
  for (int j = 0; j < 32; j += 8)
    tile[ty + j][tx] = f2bf(in[(size_t)(r0 + ty + j) * C + c0 + tx]);
  __syncthreads();
  for (int j = 0; j < 32; j += 8)
    out[(size_t)(c0 + ty + j) * R + r0 + tx] = tile[tx][ty + j];
}

// ---------------- RoPE cos/sin table: [2048 l][64 i] float2 ----------------
__global__ void rope_tab_kernel(float2* __restrict__ tab) {
  int idx = blockIdx.x * 256 + threadIdx.x;  // 2048*64
  int i = idx & 63, l = idx >> 6;
  float inv = __builtin_amdgcn_exp2f(-(float)i * (13.287712379549449f / 64.0f));
  float f = (float)l * inv;
  float s, c;
  sincosf(f, &s, &c);
  tab[idx] = make_float2(c, s);
}

// ---------------- QKV GEMM: 256x256 tile, BK=64, 8 waves, 8-phase (R8 version) ------------
__global__ __launch_bounds__(512, 2) void gemm_qkv_kernel(
    const ushort* __restrict__ A, const ushort* __restrict__ Bt,
    ushort* __restrict__ qr, ushort* __restrict__ kr, ushort* __restrict__ vt,
    const float2* __restrict__ rtab, int K, int N) {
  __shared__ __align__(16) ushort smem[65536];  // 128 KiB: [buf][A 16384 | B 16384]
  const int tid = threadIdx.x;
  const int wave = tid >> 6, lane = tid & 63;
  const int wm = wave >> 2, wn = wave & 3;  // 2 (M) x 4 (N) waves; wave tile 128x64
  const int m0 = blockIdx.y * 256, n0 = blockIdx.x * 256;
  const int frl = lane & 15, fq = lane >> 4;
  const int sx = fq ^ (frl & 7);   // ds_read phys slot base (kk adds ^ (kk<<2))
  const int srow = tid >> 3;       // staging row 0..63 within half-tile (j adds 64)
  const int slog8 = (((tid & 7) ^ ((tid >> 3) & 7)) << 3);  // pre-swizzled global col

  const ushort* aG = A + (size_t)(m0 + srow) * K + slog8;
  const ushort* bG = Bt + (size_t)(n0 + srow) * K + slog8;
  ushort* lw = smem + wave * 512;  // wave-uniform LDS staging base

  f32x4 acc[8][4] = {};
  short8 aF[4][2], bF[2][2][2];

  auto stA = [&](int tt, int h) {
    ushort* l = lw + (tt & 1) * 32768 + h * 8192;
    const ushort* g = aG + (size_t)(h * 128) * K + tt * 64;
    async_cp16(g, l);
    async_cp16(g + (size_t)64 * K, l + 4096);
  };
  auto stB = [&](int tt, int h) {
    ushort* l = lw + (tt & 1) * 32768 + 16384 + h * 8192;
    const ushort* g = bG + (size_t)(h * 128) * K + tt * 64;
    async_cp16(g, l);
    async_cp16(g + (size_t)64 * K, l + 4096);
  };
  auto LDA = [&](int buf, int mh) {
#pragma unroll
    for (int mf = 0; mf < 4; ++mf)
#pragma unroll
      for (int kk = 0; kk < 2; ++kk)
        aF[mf][kk] = *(const short8*)(smem + buf * 32768 +
            (wm * 128 + mh * 64 + mf * 16 + frl) * 64 + ((sx ^ (kk << 2)) << 3));
  };
  auto LDB = [&](int buf, int nh) {
#pragma unroll
    for (int j = 0; j < 2; ++j)
#pragma unroll
      for (int kk = 0; kk < 2; ++kk)
        bF[nh][j][kk] = *(const short8*)(smem + buf * 32768 + 16384 +
            (wn * 64 + nh * 32 + j * 16 + frl) * 64 + ((sx ^ (kk << 2)) << 3));
  };
  auto MFMAQ = [&](int mh, int nh) {
    __builtin_amdgcn_s_setprio(1);
#pragma unroll
    for (int mf = 0; mf < 4; ++mf)
#pragma unroll
      for (int j = 0; j < 2; ++j)
#pragma unroll
        for (int kk = 0; kk < 2; ++kk)
          acc[mh * 4 + mf][nh * 2 + j] = __builtin_amdgcn_mfma_f32_16x16x32_bf16(
              aF[mf][kk], bF[nh][j][kk], acc[mh * 4 + mf][nh * 2 + j], 0, 0, 0);
    __builtin_amdgcn_s_setprio(0);
  };

  // prologue: t0 fully, t1.B halves; wait t0 landed (4 newest = t1.B in flight)
  stB(0, 0); stB(0, 1); stA(0, 0); stA(0, 1);
  stB(1, 0); stB(1, 1);
  WAITVM(4);
  BARRIER;

  const int NT = K >> 6;  // 32 K-steps
  for (int i = 0; i < NT / 2 - 1; ++i) {
    const int t = 2 * i;
    LDA(0, 0); LDB(0, 0); stA(t + 1, 0);
    BARRIER; WAITLGKM; MFMAQ(0, 0); BARRIER;
    LDB(0, 1); stA(t + 1, 1);
    BARRIER; WAITLGKM; MFMAQ(0, 1); BARRIER;
    LDA(0, 1); stB(t + 2, 0);
    BARRIER; WAITLGKM; MFMAQ(1, 0); BARRIER;
    stB(t + 2, 1);
    BARRIER; WAITLGKM; MFMAQ(1, 1); WAITVM(4); BARRIER;
    LDA(1, 0); LDB(1, 0); stA(t + 2, 0);
    BARRIER; WAITLGKM; MFMAQ(0, 0); BARRIER;
    LDB(1, 1); stA(t + 2, 1);
    BARRIER; WAITLGKM; MFMAQ(0, 1); BARRIER;
    LDA(1, 1); stB(t + 3, 0);
    BARRIER; WAITLGKM; MFMAQ(1, 0); BARRIER;
    stB(t + 3, 1);
    BARRIER; WAITLGKM; MFMAQ(1, 1); WAITVM(4); BARRIER;
  }
  {  // peeled final iteration (t = NT-2): no t+2/t+3 issues; drain before buf1 reads
    const int t = NT - 2;
    LDA(0, 0); LDB(0, 0); stA(t + 1, 0);
    BARRIER; WAITLGKM; MFMAQ(0, 0); BARRIER;
    LDB(0, 1); stA(t + 1, 1);
    BARRIER; WAITLGKM; MFMAQ(0, 1); BARRIER;
    LDA(0, 1);
    BARRIER; WAITLGKM; MFMAQ(1, 0); BARRIER;
    BARRIER; WAITLGKM; MFMAQ(1, 1); WAITVM(0); BARRIER;
    LDA(1, 0); LDB(1, 0);
    BARRIER; WAITLGKM; MFMAQ(0, 0); BARRIER;
    LDB(1, 1);
    BARRIER; WAITLGKM; MFMAQ(0, 1); BARRIER;
    LDA(1, 1);
    BARRIER; WAITLGKM; MFMAQ(1, 0); BARRIER;
    BARRIER; WAITLGKM; MFMAQ(1, 1); BARRIER;
  }

  // ---- epilogue: per-wave 128x64 tile at (m0+wm*128, n0+wn*64) ----
  const int rq = fq * 4;
  if (n0 < 4096) {
    // q/k with FUSED RoPE: partner element dh^1 is at lane^1 (same mi,ni,r).
    ushort* dst = (n0 >= 2048) ? kr : qr;
#pragma unroll
    for (int mi = 0; mi < 8; ++mi)
#pragma unroll
      for (int ni = 0; ni < 4; ++ni) {
        int col = n0 + wn * 64 + ni * 16 + frl;
        int rem = col & 2047, h = rem >> 7, dh = rem & 127;
        int ip = dh >> 1;
        float sgn = (dh & 1) ? 1.0f : -1.0f;
#pragma unroll
        for (int r = 0; r < 4; ++r) {
          int row = m0 + wm * 128 + mi * 16 + rq + r;
          int b = row >> 11, l = row & 2047;
          float v = acc[mi][ni][r];
          float vp = __shfl_xor(v, 1);
          float2 cs2 = rtab[l * 64 + ip];
          float o = v * cs2.x + sgn * vp * cs2.y;
          dst[((size_t)((b << 4) + h) * 2048 + l) * 128 + dh] = f2bf(o);
        }
      }
  } else {
    // V: wave-private barrier-free LDS transpose of 16x64 slices (reuses staging smem)
    ushort* vtile = smem + wave * 1024;
    const int col0 = n0 + wn * 64;  // >= 4096
    const int row0 = m0 + wm * 128;
    const int b = row0 >> 11, l0 = row0 & 2047;
    const int swz = (frl & 3) << 4;
#pragma unroll
    for (int hm = 0; hm < 2; ++hm)
#pragma unroll
      for (int ni = 0; ni < 4; ++ni) {
#pragma unroll
        for (int mi = 0; mi < 4; ++mi)
#pragma unroll
          for (int r = 0; r < 4; ++r) {
            int ll = mi * 16 + rq + r;
            vtile[frl * 64 + (ll ^ swz)] = f2bf(acc[hm * 4 + mi][ni][r]);
          }
#pragma unroll
        for (int tt = 0; tt < 2; ++tt) {
          int dl = tt * 8 + (lane >> 3);
          int l8 = (lane & 7) * 8;
          int lsw = l8 ^ ((dl & 3) << 4);
          int rem = (col0 + ni * 16 + dl) & 2047;
          int h = rem >> 7, dh = rem & 127;
          *(short8*)(vt + ((size_t)((b << 4) + h) * 128 + dh) * 2048 + l0 + hm * 64 + l8) =
              *(const short8*)(vtile + dl * 64 + lsw);
        }
      }
  }
}

// ---------------- GEMM -> fp32 out (proj), 128x128 tile (unchanged) ----------------
__global__ __launch_bounds__(256) void gemm_out_kernel(
    const ushort* __restrict__ A, const ushort* __restrict__ Bt,
    float* __restrict__ C, int K, int N) {
  __shared__ __align__(16) ushort As[128 * 32];
  __shared__ __align__(16) ushort Bs[128 * 32];
  const int tid = threadIdx.x;
  const int wave = tid >> 6, lane = tid & 63;
  const int wr = (wave >> 1) * 64, wc = (wave & 1) * 64;
  const int m0 = blockIdx.y * 128, n0 = blockIdx.x * 128;
  const int l4 = lane >> 2, lb8 = (lane & 3) * 8;
  const int fr = lane & 15, fq8 = (lane >> 4) * 8;

  f32x4 acc[4][4] = {};

  for (int k0 = 0; k0 < K; k0 += 32) {
#pragma unroll
    for (int j = 0; j < 2; ++j) {
      const int r = wave * 32 + j * 16 + l4;
      async_cp16(A + (size_t)(m0 + r) * K + k0 + lb8, As + wave * 1024 + j * 512);
      async_cp16(Bt + (size_t)(n0 + r) * K + k0 + lb8, Bs + wave * 1024 + j * 512);
    }
    __syncthreads();
    short8 af[4], bf_[4];
#pragma unroll
    for (int i = 0; i < 4; ++i) {
      af[i] = *(const short8*)(As + (wr + i * 16 + fr) * 32 + fq8);
      bf_[i] = *(const short8*)(Bs + (wc + i * 16 + fr) * 32 + fq8);
    }
#pragma unroll
    for (int mi = 0; mi < 4; ++mi)
#pragma unroll
      for (int ni = 0; ni < 4; ++ni)
        acc[mi][ni] = __builtin_amdgcn_mfma_f32_16x16x32_bf16(af[mi], bf_[ni], acc[mi][ni], 0, 0, 0);
    __syncthreads();
  }

  const int rq = (lane >> 4) * 4;
#pragma unroll
  for (int mi = 0; mi < 4; ++mi)
#pragma unroll
    for (int ni = 0; ni < 4; ++ni) {
      int col = n0 + wc + ni * 16 + fr;
#pragma unroll
      for (int r = 0; r < 4; ++r) {
        int row = m0 + wr + mi * 16 + rq + r;
        C[(size_t)row * N + col] = acc[mi][ni][r];
      }
    }
}

// ---------------- Flash attention v7.1: 32x32x16 MFMA, shfl-based P exchange --------------
// Same as R9's v7 (2x FLOP per LDS byte; LDS-read-BW was the measured bound) but the
// P->A-frag exchange uses session-proven __shfl_xor(.,32) + per-half selects instead of
// __builtin_amdgcn_permlane32_swap (the only never-exercised element of the failed run).
// Exchange (derived, both halves checked): hi=0 -> {own0,own1,partner0,partner1};
// hi=1 -> {partner2,partner3,own2,own3}, where pk[kb][4*s2+i] are the packed bf16 pairs.
__global__ __launch_bounds__(512, 2) void flash_kernel(
    const ushort* __restrict__ qr, const ushort* __restrict__ kr,
    const ushort* __restrict__ vtg, ushort* __restrict__ att) {
  __shared__ __align__(16) ushort KV[2][16384];  // [buf][ K 64x128 | V^T 128x64 ]

  const int tid = threadIdx.x;
  const int wave = tid >> 6, lane = tid & 63;
  const int bid = blockIdx.x;
  const int swzb = (bid & 7) * 32 + (bid >> 3);  // XCD-bijective (grid 256 = 8*32)
  const int qt = swzb & 7;
  const int bh = swzb >> 3;
  const int q0 = qt * 256 + wave * 32;
  const size_t bh_base = (size_t)bh * 2048 * 128;

  const int qi = lane & 31, hi = lane >> 5;
  const float cs = 0.08838834764831845f * 1.4426950408889634f;  // scale*log2(e)
  const int rsw = (qi & 7) << 3;  // read-side XOR swizzle (row&7 == qi&7 for all reads)

  // staging geometry (identical to v6.1): per wave, pass i=0,1: one K + one V cp16
  const int krow0 = wave * 8 + (lane >> 4);
  const int kgc = (lane & 15) * 8;
  const int vrow0 = wave * 16 + (lane >> 3);
  const int vgc = (lane & 7) * 8;

  auto stage = [&](int kt, int buf) {
#pragma unroll
    for (int i = 0; i < 2; ++i) {
      const int krow = krow0 + i * 4;
      async_cp16(kr + bh_base + (size_t)(kt * 64 + krow) * 128 + (kgc ^ ((krow & 7) << 3)),
                 &KV[buf][(wave * 2 + i) * 512]);
      const int vrow = vrow0 + i * 8;
      async_cp16(vtg + bh_base + (size_t)vrow * 2048 + kt * 64 + (vgc ^ ((vrow & 7) << 3)),
                 &KV[buf][8192 + (wave * 2 + i) * 512]);
    }
  };

  // Q preload: q-row = q0+qi; elems c*16 + hi*8 .. +8  (B-frag k = 8*hi+j)
  short8 qf[8];
  {
    const ushort* qp = qr + bh_base + (size_t)(q0 + qi) * 128 + hi * 8;
#pragma unroll
    for (int c = 0; c < 8; ++c) qf[c] = *(const short8*)(qp + c * 16);
  }

  f32x16 oacc[4];
#pragma unroll
  for (int nt = 0; nt < 4; ++nt)
#pragma unroll
    for (int r = 0; r < 16; ++r) oacc[nt][r] = 0.f;
  float l_lane = 0.f;

  stage(0, 0);
  stage(1, 1);
  WAITVM(4);
  BARRIER;

#pragma unroll 2
  for (int kt = 0; kt < 32; ++kt) {
    const int bo = (kt & 1) * 16384;
    const ushort* kv = &KV[0][0];

    // ---- S^T = K Q^T (swapped, both 32-key blocks interleaved for ILP) ----
    f32x16 s0, s1;
#pragma unroll
    for (int r = 0; r < 16; ++r) { s0[r] = 0.f; s1[r] = 0.f; }
    const ushort* kp0 = kv + bo + (size_t)(0 * 32 + qi) * 128;
    const ushort* kp1 = kv + bo + (size_t)(1 * 32 + qi) * 128;
    __builtin_amdgcn_s_setprio(1);
#pragma unroll
    for (int c = 0; c < 8; ++c) {
      const int co = (c * 16 + hi * 8) ^ rsw;
      short8 kf0 = *(const short8*)(kp0 + co);
      short8 kf1 = *(const short8*)(kp1 + co);
      s0 = __builtin_amdgcn_mfma_f32_32x32x16_bf16(kf0, qf[c], s0, 0, 0, 0);
      s1 = __builtin_amdgcn_mfma_f32_32x32x16_bf16(kf1, qf[c], s1, 0, 0, 0);
    }
    __builtin_amdgcn_s_setprio(0);

    // ---- in-register softmax: exp2 + pack into bf16 dword pairs (reg-pair order) ----
    int pk[2][8];
#pragma unroll
    for (int m = 0; m < 8; ++m) {
      float a0 = __builtin_amdgcn_exp2f(s0[2 * m] * cs);
      float a1 = __builtin_amdgcn_exp2f(s0[2 * m + 1] * cs);
      float b0 = __builtin_amdgcn_exp2f(s1[2 * m] * cs);
      float b1 = __builtin_amdgcn_exp2f(s1[2 * m + 1] * cs);
      l_lane += (a0 + a1) + (b0 + b1);
      pk[0][m] = (int)f2bf(a0) | ((int)f2bf(a1) << 16);
      pk[1][m] = (int)f2bf(b0) | ((int)f2bf(b1) << 16);
    }

    // ---- O += P V : A-frag via shfl_xor(32) exchange; V^T b128 reads ----
    __builtin_amdgcn_s_setprio(1);
#pragma unroll
    for (int ks = 0; ks < 4; ++ks) {
      const int kb = ks >> 1, s2 = ks & 1;
      const int a0 = pk[kb][4 * s2 + 0], a1 = pk[kb][4 * s2 + 1];
      const int a2 = pk[kb][4 * s2 + 2], a3 = pk[kb][4 * s2 + 3];
      const int p0 = __shfl_xor(a0, 32), p1 = __shfl_xor(a1, 32);
      const int p2 = __shfl_xor(a2, 32), p3 = __shfl_xor(a3, 32);
      i32x4 w;
      w[0] = hi ? p2 : a0;
      w[1] = hi ? p3 : a1;
      w[2] = hi ? a2 : p0;
      w[3] = hi ? a3 : p1;
      short8 pa = __builtin_bit_cast(short8, w);
      const int vco = (ks * 16 + hi * 8) ^ rsw;
#pragma unroll
      for (int nt = 0; nt < 4; ++nt) {
        short8 vf = *(const short8*)(kv + bo + 8192 + (size_t)(nt * 32 + qi) * 64 + vco);
        oacc[nt] = __builtin_amdgcn_mfma_f32_32x32x16_bf16(pa, vf, oacc[nt], 0, 0, 0);
      }
    }
    __builtin_amdgcn_s_setprio(0);

    BARRIER;  // all waves done reading buf (kt&1) before overwrite
    if (kt < 30) {
      stage(kt + 2, kt & 1);
      WAITVM(4);
    } else {
      WAITVM(0);
    }
    BARRIER;  // publish t(kt+1)
  }

  // ---- epilogue: l[q] = both hi-halves; store O rows crow(r,hi) ----
  l_lane += __shfl_xor(l_lane, 32);
  const float linv = 1.0f / l_lane;  // valid for q = qi on every lane
  const int b = bh >> 4, h = bh & 15;
#pragma unroll
  for (int r = 0; r < 16; ++r) {
    const int crow = (r & 3) + 8 * (r >> 2) + 4 * hi;
    const float inv = __shfl(linv, crow);
    const size_t rowa = (size_t)(b * 2048 + q0 + crow) * 2048 + h * 128;
#pragma unroll
    for (int nt = 0; nt < 4; ++nt)
      att[rowa + nt * 32 + qi] = f2bf(oacc[nt][r] * inv);
  }
}

extern "C" void kernel_launch(void* const* d_in, const int* in_sizes, int n_in,
                              void* d_out, int out_size, void* d_ws, size_t ws_size,
                              hipStream_t stream) {
  const float* x = (const float*)d_in[0];       // [2,2048,2048]
  const float* w_qkv = (const float*)d_in[1];   // [2048,6144]
  const float* w_proj = (const float*)d_in[2];  // [2048,2048]
  float* out = (float*)d_out;                   // [2,2048,2048] fp32

  char* p = (char*)d_ws;
  ushort* xb = (ushort*)p;  p += (size_t)4096 * 2048 * 2;
  ushort* wqt = (ushort*)p; p += (size_t)6144 * 2048 * 2;
  ushort* wpt = (ushort*)p; p += (size_t)2048 * 2048 * 2;
  ushort* qr = (ushort*)p;  p += (size_t)32 * 2048 * 128 * 2;
  ushort* kr = (ushort*)p;  p += (size_t)32 * 2048 * 128 * 2;
  ushort* vt = (ushort*)p;  p += (size_t)32 * 2048 * 128 * 2;  // [bh][128][2048]
  ushort* att = (ushort*)p; p += (size_t)4096 * 2048 * 2;
  float2* rtab = (float2*)p; p += (size_t)2048 * 64 * 8;       // 1 MB cos/sin table

  rope_tab_kernel<<<512, 256, 0, stream>>>(rtab);
  cvt_bf16_kernel<<<8192, 256, 0, stream>>>(x, xb, 4096 * 2048 / 4);
  transpose_cvt_kernel<<<dim3(192, 64), dim3(32, 8), 0, stream>>>(w_qkv, wqt, 2048, 6144);
  transpose_cvt_kernel<<<dim3(64, 64), dim3(32, 8), 0, stream>>>(w_proj, wpt, 2048, 2048);
  gemm_qkv_kernel<<<dim3(24, 16), 512, 0, stream>>>(xb, wqt, qr, kr, vt, rtab, 2048, 6144);
  flash_kernel<<<256, 512, 0, stream>>>(qr, kr, vt, att);
  gemm_out_kernel<<<dim3(16, 32), 256, 0, stream>>>(att, wpt, out, 2048, 2048);
}

// Round 11
// 391.789 us; speedup vs baseline: 1.1125x; 1.0298x over previous
//
#include <hip/hip_runtime.h>
#include <hip/hip_bf16.h>
#include <cstdint>

// B=2, L=2048, D=2048, H=16, HD=128 ; M = B*L = 4096, Nqkv = 6144
typedef short short8 __attribute__((ext_vector_type(8)));
typedef float f32x4 __attribute__((ext_vector_type(4)));
typedef float f32x16 __attribute__((ext_vector_type(16)));
typedef int i32x4 __attribute__((ext_vector_type(4)));

#define AS1 __attribute__((address_space(1)))
#define AS3 __attribute__((address_space(3)))

static __device__ __forceinline__ void async_cp16(const void* g, void* l) {
  __builtin_amdgcn_global_load_lds((const AS1 unsigned int*)g, (AS3 unsigned int*)l, 16, 0, 0);
}

static __device__ __forceinline__ ushort f2bf(float f) {
  unsigned u = __builtin_bit_cast(unsigned, f);
  u += 0x7fffu + ((u >> 16) & 1u);
  return (ushort)(u >> 16);
}
static __device__ __forceinline__ float bf2f(ushort h) {
  unsigned u = ((unsigned)h) << 16;
  return __builtin_bit_cast(float, u);
}

#define FENCE asm volatile("" ::: "memory")
#define BARRIER do { FENCE; __builtin_amdgcn_s_barrier(); FENCE; } while (0)
#define WAITLGKM asm volatile("s_waitcnt lgkmcnt(0)" ::: "memory")
#define WAITVM(N) asm volatile("s_waitcnt vmcnt(" #N ")" ::: "memory")

// ---------------- fp32 -> bf16 convert (x) ----------------
__global__ void cvt_bf16_kernel(const float* __restrict__ in, ushort* __restrict__ out, int n4) {
  int i = blockIdx.x * blockDim.x + threadIdx.x;
  if (i >= n4) return;
  float4 v = ((const float4*)in)[i];
  ushort4 o;
  o.x = f2bf(v.x); o.y = f2bf(v.y); o.z = f2bf(v.z); o.w = f2bf(v.w);
  ((ushort4*)out)[i] = o;
}

// ---------------- fp32 [R][C] -> bf16 [C][R] (weights to B^T layout) ----------------
__global__ void transpose_cvt_kernel(const float* __restrict__ in, ushort* __restrict__ out,
                                     int R, int C) {
  __shared__ ushort tile[32][33];
  int c0 = blockIdx.x * 32, r0 = blockIdx.y * 32;
  int tx = threadIdx.x, ty = threadIdx.y;  // 32 x 8
  for (int j = 0; j < 32; j += 8)
    tile[ty + j][tx] = f2bf(in[(size_t)(r0 + ty + j) * C + c0 + tx]);
  __syncthreads();
  for (int j = 0; j < 32; j += 8)
    out[(size_t)(c0 + ty + j) * R + r0 + tx] = tile[tx][ty + j];
}

// ---------------- RoPE cos/sin table: [2048 l][64 i] float2 ----------------
__global__ void rope_tab_kernel(float2* __restrict__ tab) {
  int idx = blockIdx.x * 256 + threadIdx.x;  // 2048*64
  int i = idx & 63, l = idx >> 6;
  float inv = __builtin_amdgcn_exp2f(-(float)i * (13.287712379549449f / 64.0f));
  float f = (float)l * inv;
  float s, c;
  sincosf(f, &s, &c);
  tab[idx] = make_float2(c, s);
}

// ---------------- QKV GEMM: 256x256 tile, BK=64, 8 waves, 8-phase (unchanged R10) ---------
__global__ __launch_bounds__(512, 2) void gemm_qkv_kernel(
    const ushort* __restrict__ A, const ushort* __restrict__ Bt,
    ushort* __restrict__ qr, ushort* __restrict__ kr, ushort* __restrict__ vt,
    const float2* __restrict__ rtab, int K, int N) {
  __shared__ __align__(16) ushort smem[65536];  // 128 KiB: [buf][A 16384 | B 16384]
  const int tid = threadIdx.x;
  const int wave = tid >> 6, lane = tid & 63;
  const int wm = wave >> 2, wn = wave & 3;  // 2 (M) x 4 (N) waves; wave tile 128x64
  const int m0 = blockIdx.y * 256, n0 = blockIdx.x * 256;
  const int frl = lane & 15, fq = lane >> 4;
  const int sx = fq ^ (frl & 7);   // ds_read phys slot base (kk adds ^ (kk<<2))
  const int srow = tid >> 3;       // staging row 0..63 within half-tile (j adds 64)
  const int slog8 = (((tid & 7) ^ ((tid >> 3) & 7)) << 3);  // pre-swizzled global col

  const ushort* aG = A + (size_t)(m0 + srow) * K + slog8;
  const ushort* bG = Bt + (size_t)(n0 + srow) * K + slog8;
  ushort* lw = smem + wave * 512;  // wave-uniform LDS staging base

  f32x4 acc[8][4] = {};
  short8 aF[4][2], bF[2][2][2];

  auto stA = [&](int tt, int h) {
    ushort* l = lw + (tt & 1) * 32768 + h * 8192;
    const ushort* g = aG + (size_t)(h * 128) * K + tt * 64;
    async_cp16(g, l);
    async_cp16(g + (size_t)64 * K, l + 4096);
  };
  auto stB = [&](int tt, int h) {
    ushort* l = lw + (tt & 1) * 32768 + 16384 + h * 8192;
    const ushort* g = bG + (size_t)(h * 128) * K + tt * 64;
    async_cp16(g, l);
    async_cp16(g + (size_t)64 * K, l + 4096);
  };
  auto LDA = [&](int buf, int mh) {
#pragma unroll
    for (int mf = 0; mf < 4; ++mf)
#pragma unroll
      for (int kk = 0; kk < 2; ++kk)
        aF[mf][kk] = *(const short8*)(smem + buf * 32768 +
            (wm * 128 + mh * 64 + mf * 16 + frl) * 64 + ((sx ^ (kk << 2)) << 3));
  };
  auto LDB = [&](int buf, int nh) {
#pragma unroll
    for (int j = 0; j < 2; ++j)
#pragma unroll
      for (int kk = 0; kk < 2; ++kk)
        bF[nh][j][kk] = *(const short8*)(smem + buf * 32768 + 16384 +
            (wn * 64 + nh * 32 + j * 16 + frl) * 64 + ((sx ^ (kk << 2)) << 3));
  };
  auto MFMAQ = [&](int mh, int nh) {
    __builtin_amdgcn_s_setprio(1);
#pragma unroll
    for (int mf = 0; mf < 4; ++mf)
#pragma unroll
      for (int j = 0; j < 2; ++j)
#pragma unroll
        for (int kk = 0; kk < 2; ++kk)
          acc[mh * 4 + mf][nh * 2 + j] = __builtin_amdgcn_mfma_f32_16x16x32_bf16(
              aF[mf][kk], bF[nh][j][kk], acc[mh * 4 + mf][nh * 2 + j], 0, 0, 0);
    __builtin_amdgcn_s_setprio(0);
  };

  // prologue: t0 fully, t1.B halves; wait t0 landed (4 newest = t1.B in flight)
  stB(0, 0); stB(0, 1); stA(0, 0); stA(0, 1);
  stB(1, 0); stB(1, 1);
  WAITVM(4);
  BARRIER;

  const int NT = K >> 6;  // 32 K-steps
  for (int i = 0; i < NT / 2 - 1; ++i) {
    const int t = 2 * i;
    LDA(0, 0); LDB(0, 0); stA(t + 1, 0);
    BARRIER; WAITLGKM; MFMAQ(0, 0); BARRIER;
    LDB(0, 1); stA(t + 1, 1);
    BARRIER; WAITLGKM; MFMAQ(0, 1); BARRIER;
    LDA(0, 1); stB(t + 2, 0);
    BARRIER; WAITLGKM; MFMAQ(1, 0); BARRIER;
    stB(t + 2, 1);
    BARRIER; WAITLGKM; MFMAQ(1, 1); WAITVM(4); BARRIER;
    LDA(1, 0); LDB(1, 0); stA(t + 2, 0);
    BARRIER; WAITLGKM; MFMAQ(0, 0); BARRIER;
    LDB(1, 1); stA(t + 2, 1);
    BARRIER; WAITLGKM; MFMAQ(0, 1); BARRIER;
    LDA(1, 1); stB(t + 3, 0);
    BARRIER; WAITLGKM; MFMAQ(1, 0); BARRIER;
    stB(t + 3, 1);
    BARRIER; WAITLGKM; MFMAQ(1, 1); WAITVM(4); BARRIER;
  }
  {  // peeled final iteration (t = NT-2): no t+2/t+3 issues; drain before buf1 reads
    const int t = NT - 2;
    LDA(0, 0); LDB(0, 0); stA(t + 1, 0);
    BARRIER; WAITLGKM; MFMAQ(0, 0); BARRIER;
    LDB(0, 1); stA(t + 1, 1);
    BARRIER; WAITLGKM; MFMAQ(0, 1); BARRIER;
    LDA(0, 1);
    BARRIER; WAITLGKM; MFMAQ(1, 0); BARRIER;
    BARRIER; WAITLGKM; MFMAQ(1, 1); WAITVM(0); BARRIER;
    LDA(1, 0); LDB(1, 0);
    BARRIER; WAITLGKM; MFMAQ(0, 0); BARRIER;
    LDB(1, 1);
    BARRIER; WAITLGKM; MFMAQ(0, 1); BARRIER;
    LDA(1, 1);
    BARRIER; WAITLGKM; MFMAQ(1, 0); BARRIER;
    BARRIER; WAITLGKM; MFMAQ(1, 1); BARRIER;
  }

  // ---- epilogue: per-wave 128x64 tile at (m0+wm*128, n0+wn*64) ----
  const int rq = fq * 4;
  if (n0 < 4096) {
    // q/k with FUSED RoPE: partner element dh^1 is at lane^1 (same mi,ni,r).
    ushort* dst = (n0 >= 2048) ? kr : qr;
#pragma unroll
    for (int mi = 0; mi < 8; ++mi)
#pragma unroll
      for (int ni = 0; ni < 4; ++ni) {
        int col = n0 + wn * 64 + ni * 16 + frl;
        int rem = col & 2047, h = rem >> 7, dh = rem & 127;
        int ip = dh >> 1;
        float sgn = (dh & 1) ? 1.0f : -1.0f;
#pragma unroll
        for (int r = 0; r < 4; ++r) {
          int row = m0 + wm * 128 + mi * 16 + rq + r;
          int b = row >> 11, l = row & 2047;
          float v = acc[mi][ni][r];
          float vp = __shfl_xor(v, 1);
          float2 cs2 = rtab[l * 64 + ip];
          float o = v * cs2.x + sgn * vp * cs2.y;
          dst[((size_t)((b << 4) + h) * 2048 + l) * 128 + dh] = f2bf(o);
        }
      }
  } else {
    // V: wave-private barrier-free LDS transpose of 16x64 slices (reuses staging smem)
    ushort* vtile = smem + wave * 1024;
    const int col0 = n0 + wn * 64;  // >= 4096
    const int row0 = m0 + wm * 128;
    const int b = row0 >> 11, l0 = row0 & 2047;
    const int swz = (frl & 3) << 4;
#pragma unroll
    for (int hm = 0; hm < 2; ++hm)
#pragma unroll
      for (int ni = 0; ni < 4; ++ni) {
#pragma unroll
        for (int mi = 0; mi < 4; ++mi)
#pragma unroll
          for (int r = 0; r < 4; ++r) {
            int ll = mi * 16 + rq + r;
            vtile[frl * 64 + (ll ^ swz)] = f2bf(acc[hm * 4 + mi][ni][r]);
          }
#pragma unroll
        for (int tt = 0; tt < 2; ++tt) {
          int dl = tt * 8 + (lane >> 3);
          int l8 = (lane & 7) * 8;
          int lsw = l8 ^ ((dl & 3) << 4);
          int rem = (col0 + ni * 16 + dl) & 2047;
          int h = rem >> 7, dh = rem & 127;
          *(short8*)(vt + ((size_t)((b << 4) + h) * 128 + dh) * 2048 + l0 + hm * 64 + l8) =
              *(const short8*)(vtile + dl * 64 + lsw);
        }
      }
  }
}

// ---------------- GEMM -> fp32 out (proj) v2: 128x256 tile, BK=64, 8-phase ----------------
// Port of the qkv template: grid (8,32) = 256 blocks = exactly 1/CU (no quantization;
// old 128^2 structure ran 512 blocks at 435 TF). LDS 96 KiB = (128+256)x64x2B x2buf.
// 8 waves as 2(M)x4(N), wave tile 64x64, acc[4][4]. Issue slots re-derived: A(t+1)@ph1
// (buf1-A reads end prev ph7), stB(t+2,0)@ph3 (buf0-B reads end ph2), stB(t+2,1)@ph4;
// FIFO gate vmcnt(4) = next tile's 4 B-loads outstanding, mirror of qkv's proof.
__global__ __launch_bounds__(512, 2) void gemm_out_kernel(
    const ushort* __restrict__ A, const ushort* __restrict__ Bt,
    float* __restrict__ C, int K, int N) {
  __shared__ __align__(16) ushort smem[49152];  // 96 KiB: [buf][A 8192 | B 16384]
  const int tid = threadIdx.x;
  const int wave = tid >> 6, lane = tid & 63;
  const int wm = wave >> 2, wn = wave & 3;  // 2(M) x 4(N); wave tile 64x64
  const int m0 = blockIdx.y * 128, n0 = blockIdx.x * 256;
  const int frl = lane & 15, fq = lane >> 4;
  const int sx = fq ^ (frl & 7);
  const int srow = tid >> 3;
  const int slog8 = (((tid & 7) ^ ((tid >> 3) & 7)) << 3);

  const ushort* aG = A + (size_t)(m0 + srow) * K + slog8;
  const ushort* bG = Bt + (size_t)(n0 + srow) * K + slog8;
  ushort* lw = smem + wave * 512;

  f32x4 acc[4][4] = {};
  short8 aF[2][2], bF[2][2][2];

  auto stA = [&](int tt) {  // A rows 0..127 (2 loads)
    ushort* l = lw + (tt & 1) * 24576;
    const ushort* g = aG + tt * 64;
    async_cp16(g, l);
    async_cp16(g + (size_t)64 * K, l + 4096);
  };
  auto stB = [&](int tt, int h) {  // B rows h*128..h*128+127 (2 loads)
    ushort* l = lw + (tt & 1) * 24576 + 8192 + h * 8192;
    const ushort* g = bG + (size_t)(h * 128) * K + tt * 64;
    async_cp16(g, l);
    async_cp16(g + (size_t)64 * K, l + 4096);
  };
  auto LDA = [&](int buf, int mh) {
#pragma unroll
    for (int mf = 0; mf < 2; ++mf)
#pragma unroll
      for (int kk = 0; kk < 2; ++kk)
        aF[mf][kk] = *(const short8*)(smem + buf * 24576 +
            (wm * 64 + mh * 32 + mf * 16 + frl) * 64 + ((sx ^ (kk << 2)) << 3));
  };
  auto LDB = [&](int buf, int nh) {
#pragma unroll
    for (int j = 0; j < 2; ++j)
#pragma unroll
      for (int kk = 0; kk < 2; ++kk)
        bF[nh][j][kk] = *(const short8*)(smem + buf * 24576 + 8192 +
            (wn * 64 + nh * 32 + j * 16 + frl) * 64 + ((sx ^ (kk << 2)) << 3));
  };
  auto MFMAQ = [&](int mh, int nh) {
    __builtin_amdgcn_s_setprio(1);
#pragma unroll
    for (int mf = 0; mf < 2; ++mf)
#pragma unroll
      for (int j = 0; j < 2; ++j)
#pragma unroll
        for (int kk = 0; kk < 2; ++kk)
          acc[mh * 2 + mf][nh * 2 + j] = __builtin_amdgcn_mfma_f32_16x16x32_bf16(
              aF[mf][kk], bF[nh][j][kk], acc[mh * 2 + mf][nh * 2 + j], 0, 0, 0);
    __builtin_amdgcn_s_setprio(0);
  };

  // prologue: t0 fully (6), t1's B (4); vmcnt(4) -> t0 landed, t1.B in flight
  stB(0, 0); stB(0, 1); stA(0);
  stB(1, 0); stB(1, 1);
  WAITVM(4);
  BARRIER;

  const int NT = K >> 6;  // 32 K-steps
  for (int i = 0; i < NT / 2 - 1; ++i) {
    const int t = 2 * i;
    LDA(0, 0); LDB(0, 0); stA(t + 1);
    BARRIER; WAITLGKM; MFMAQ(0, 0); BARRIER;
    LDB(0, 1);
    BARRIER; WAITLGKM; MFMAQ(0, 1); BARRIER;
    LDA(0, 1); stB(t + 2, 0);
    BARRIER; WAITLGKM; MFMAQ(1, 0); BARRIER;
    stB(t + 2, 1);
    BARRIER; WAITLGKM; MFMAQ(1, 1); WAITVM(4); BARRIER;
    LDA(1, 0); LDB(1, 0); stA(t + 2);
    BARRIER; WAITLGKM; MFMAQ(0, 0); BARRIER;
    LDB(1, 1);
    BARRIER; WAITLGKM; MFMAQ(0, 1); BARRIER;
    LDA(1, 1); stB(t + 3, 0);
    BARRIER; WAITLGKM; MFMAQ(1, 0); BARRIER;
    stB(t + 3, 1);
    BARRIER; WAITLGKM; MFMAQ(1, 1); WAITVM(4); BARRIER;
  }
  {  // peeled final iteration (t = NT-2)
    const int t = NT - 2;
    LDA(0, 0); LDB(0, 0); stA(t + 1);
    BARRIER; WAITLGKM; MFMAQ(0, 0); BARRIER;
    LDB(0, 1);
    BARRIER; WAITLGKM; MFMAQ(0, 1); BARRIER;
    LDA(0, 1);
    BARRIER; WAITLGKM; MFMAQ(1, 0); BARRIER;
    BARRIER; WAITLGKM; MFMAQ(1, 1); WAITVM(0); BARRIER;
    LDA(1, 0); LDB(1, 0);
    BARRIER; WAITLGKM; MFMAQ(0, 0); BARRIER;
    LDB(1, 1);
    BARRIER; WAITLGKM; MFMAQ(0, 1); BARRIER;
    LDA(1, 1);
    BARRIER; WAITLGKM; MFMAQ(1, 0); BARRIER;
    BARRIER; WAITLGKM; MFMAQ(1, 1); BARRIER;
  }

  // ---- epilogue: plain fp32 C write; wave tile 64x64 at (m0+wm*64, n0+wn*64) ----
  const int rq = fq * 4;
#pragma unroll
  for (int mi = 0; mi < 4; ++mi)
#pragma unroll
    for (int nj = 0; nj < 4; ++nj) {
      int col = n0 + wn * 64 + nj * 16 + frl;
#pragma unroll
      for (int r = 0; r < 4; ++r) {
        int row = m0 + wm * 64 + mi * 16 + rq + r;
        C[(size_t)row * N + col] = acc[mi][nj][r];
      }
    }
}

// ---------------- Flash attention v7.1 (unchanged R10): 32x32x16, shfl P-exchange ---------
__global__ __launch_bounds__(512, 2) void flash_kernel(
    const ushort* __restrict__ qr, const ushort* __restrict__ kr,
    const ushort* __restrict__ vtg, ushort* __restrict__ att) {
  __shared__ __align__(16) ushort KV[2][16384];  // [buf][ K 64x128 | V^T 128x64 ]

  const int tid = threadIdx.x;
  const int wave = tid >> 6, lane = tid & 63;
  const int bid = blockIdx.x;
  const int swzb = (bid & 7) * 32 + (bid >> 3);  // XCD-bijective (grid 256 = 8*32)
  const int qt = swzb & 7;
  const int bh = swzb >> 3;
  const int q0 = qt * 256 + wave * 32;
  const size_t bh_base = (size_t)bh * 2048 * 128;

  const int qi = lane & 31, hi = lane >> 5;
  const float cs = 0.08838834764831845f * 1.4426950408889634f;  // scale*log2(e)
  const int rsw = (qi & 7) << 3;  // read-side XOR swizzle (row&7 == qi&7 for all reads)

  const int krow0 = wave * 8 + (lane >> 4);
  const int kgc = (lane & 15) * 8;
  const int vrow0 = wave * 16 + (lane >> 3);
  const int vgc = (lane & 7) * 8;

  auto stage = [&](int kt, int buf) {
#pragma unroll
    for (int i = 0; i < 2; ++i) {
      const int krow = krow0 + i * 4;
      async_cp16(kr + bh_base + (size_t)(kt * 64 + krow) * 128 + (kgc ^ ((krow & 7) << 3)),
                 &KV[buf][(wave * 2 + i) * 512]);
      const int vrow = vrow0 + i * 8;
      async_cp16(vtg + bh_base + (size_t)vrow * 2048 + kt * 64 + (vgc ^ ((vrow & 7) << 3)),
                 &KV[buf][8192 + (wave * 2 + i) * 512]);
    }
  };

  short8 qf[8];
  {
    const ushort* qp = qr + bh_base + (size_t)(q0 + qi) * 128 + hi * 8;
#pragma unroll
    for (int c = 0; c < 8; ++c) qf[c] = *(const short8*)(qp + c * 16);
  }

  f32x16 oacc[4];
#pragma unroll
  for (int nt = 0; nt < 4; ++nt)
#pragma unroll
    for (int r = 0; r < 16; ++r) oacc[nt][r] = 0.f;
  float l_lane = 0.f;

  stage(0, 0);
  stage(1, 1);
  WAITVM(4);
  BARRIER;

#pragma unroll 2
  for (int kt = 0; kt < 32; ++kt) {
    const int bo = (kt & 1) * 16384;
    const ushort* kv = &KV[0][0];

    f32x16 s0, s1;
#pragma unroll
    for (int r = 0; r < 16; ++r) { s0[r] = 0.f; s1[r] = 0.f; }
    const ushort* kp0 = kv + bo + (size_t)(0 * 32 + qi) * 128;
    const ushort* kp1 = kv + bo + (size_t)(1 * 32 + qi) * 128;
    __builtin_amdgcn_s_setprio(1);
#pragma unroll
    for (int c = 0; c < 8; ++c) {
      const int co = (c * 16 + hi * 8) ^ rsw;
      short8 kf0 = *(const short8*)(kp0 + co);
      short8 kf1 = *(const short8*)(kp1 + co);
      s0 = __builtin_amdgcn_mfma_f32_32x32x16_bf16(kf0, qf[c], s0, 0, 0, 0);
      s1 = __builtin_amdgcn_mfma_f32_32x32x16_bf16(kf1, qf[c], s1, 0, 0, 0);
    }
    __builtin_amdgcn_s_setprio(0);

    int pk[2][8];
#pragma unroll
    for (int m = 0; m < 8; ++m) {
      float a0 = __builtin_amdgcn_exp2f(s0[2 * m] * cs);
      float a1 = __builtin_amdgcn_exp2f(s0[2 * m + 1] * cs);
      float b0 = __builtin_amdgcn_exp2f(s1[2 * m] * cs);
      float b1 = __builtin_amdgcn_exp2f(s1[2 * m + 1] * cs);
      l_lane += (a0 + a1) + (b0 + b1);
      pk[0][m] = (int)f2bf(a0) | ((int)f2bf(a1) << 16);
      pk[1][m] = (int)f2bf(b0) | ((int)f2bf(b1) << 16);
    }

    __builtin_amdgcn_s_setprio(1);
#pragma unroll
    for (int ks = 0; ks < 4; ++ks) {
      const int kb = ks >> 1, s2 = ks & 1;
      const int a0 = pk[kb][4 * s2 + 0], a1 = pk[kb][4 * s2 + 1];
      const int a2 = pk[kb][4 * s2 + 2], a3 = pk[kb][4 * s2 + 3];
      const int p0 = __shfl_xor(a0, 32), p1 = __shfl_xor(a1, 32);
      const int p2 = __shfl_xor(a2, 32), p3 = __shfl_xor(a3, 32);
      i32x4 w;
      w[0] = hi ? p2 : a0;
      w[1] = hi ? p3 : a1;
      w[2] = hi ? a2 : p0;
      w[3] = hi ? a3 : p1;
      short8 pa = __builtin_bit_cast(short8, w);
      const int vco = (ks * 16 + hi * 8) ^ rsw;
#pragma unroll
      for (int nt = 0; nt < 4; ++nt) {
        short8 vf = *(const short8*)(kv + bo + 8192 + (size_t)(nt * 32 + qi) * 64 + vco);
        oacc[nt] = __builtin_amdgcn_mfma_f32_32x32x16_bf16(pa, vf, oacc[nt], 0, 0, 0);
      }
    }
    __builtin_amdgcn_s_setprio(0);

    BARRIER;
    if (kt < 30) {
      stage(kt + 2, kt & 1);
      WAITVM(4);
    } else {
      WAITVM(0);
    }
    BARRIER;
  }

  l_lane += __shfl_xor(l_lane, 32);
  const float linv = 1.0f / l_lane;
  const int b = bh >> 4, h = bh & 15;
#pragma unroll
  for (int r = 0; r < 16; ++r) {
    const int crow = (r & 3) + 8 * (r >> 2) + 4 * hi;
    const float inv = __shfl(linv, crow);
    const size_t rowa = (size_t)(b * 2048 + q0 + crow) * 2048 + h * 128;
#pragma unroll
    for (int nt = 0; nt < 4; ++nt)
      att[rowa + nt * 32 + qi] = f2bf(oacc[nt][r] * inv);
  }
}

extern "C" void kernel_launch(void* const* d_in, const int* in_sizes, int n_in,
                              void* d_out, int out_size, void* d_ws, size_t ws_size,
                              hipStream_t stream) {
  const float* x = (const float*)d_in[0];       // [2,2048,2048]
  const float* w_qkv = (const float*)d_in[1];   // [2048,6144]
  const float* w_proj = (const float*)d_in[2];  // [2048,2048]
  float* out = (float*)d_out;                   // [2,2048,2048] fp32

  char* p = (char*)d_ws;
  ushort* xb = (ushort*)p;  p += (size_t)4096 * 2048 * 2;
  ushort* wqt = (ushort*)p; p += (size_t)6144 * 2048 * 2;
  ushort* wpt = (ushort*)p; p += (size_t)2048 * 2048 * 2;
  ushort* qr = (ushort*)p;  p += (size_t)32 * 2048 * 128 * 2;
  ushort* kr = (ushort*)p;  p += (size_t)32 * 2048 * 128 * 2;
  ushort* vt = (ushort*)p;  p += (size_t)32 * 2048 * 128 * 2;  // [bh][128][2048]
  ushort* att = (ushort*)p; p += (size_t)4096 * 2048 * 2;
  float2* rtab = (float2*)p; p += (size_t)2048 * 64 * 8;       // 1 MB cos/sin table

  rope_tab_kernel<<<512, 256, 0, stream>>>(rtab);
  cvt_bf16_kernel<<<8192, 256, 0, stream>>>(x, xb, 4096 * 2048 / 4);
  transpose_cvt_kernel<<<dim3(192, 64), dim3(32, 8), 0, stream>>>(w_qkv, wqt, 2048, 6144);
  transpose_cvt_kernel<<<dim3(64, 64), dim3(32, 8), 0, stream>>>(w_proj, wpt, 2048, 2048);
  gemm_qkv_kernel<<<dim3(24, 16), 512, 0, stream>>>(xb, wqt, qr, kr, vt, rtab, 2048, 6144);
  flash_kernel<<<256, 512, 0, stream>>>(qr, kr, vt, att);
  gemm_out_kernel<<<dim3(8, 32), 512, 0, stream>>>(att, wpt, out, 2048, 2048);
}

// Round 12
// 380.795 us; speedup vs baseline: 1.1446x; 1.0289x over previous
//
#include <hip/hip_runtime.h>
#include <hip/hip_bf16.h>
#include <cstdint>

// B=2, L=2048, D=2048, H=16, HD=128 ; M = B*L = 4096, Nqkv = 6144
typedef short short8 __attribute__((ext_vector_type(8)));
typedef float f32x4 __attribute__((ext_vector_type(4)));
typedef float f32x16 __attribute__((ext_vector_type(16)));
typedef int i32x4 __attribute__((ext_vector_type(4)));

#define AS1 __attribute__((address_space(1)))
#define AS3 __attribute__((address_space(3)))

static __device__ __forceinline__ void async_cp16(const void* g, void* l) {
  __builtin_amdgcn_global_load_lds((const AS1 unsigned int*)g, (AS3 unsigned int*)l, 16, 0, 0);
}

static __device__ __forceinline__ ushort f2bf(float f) {
  unsigned u = __builtin_bit_cast(unsigned, f);
  u += 0x7fffu + ((u >> 16) & 1u);
  return (ushort)(u >> 16);
}
static __device__ __forceinline__ float bf2f(ushort h) {
  unsigned u = ((unsigned)h) << 16;
  return __builtin_bit_cast(float, u);
}

#define FENCE asm volatile("" ::: "memory")
#define BARRIER do { FENCE; __builtin_amdgcn_s_barrier(); FENCE; } while (0)
#define WAITLGKM asm volatile("s_waitcnt lgkmcnt(0)" ::: "memory")
#define WAITVM(N) asm volatile("s_waitcnt vmcnt(" #N ")" ::: "memory")

// ---------------- Fused preprocessing: cvt(x) + rope table + both weight transposes ------
// One launch instead of four (saves ~3 inter-kernel gaps). Transpose store phase widened
// to ushort2 (128 B per half-wave vs 64 B scalar).
__global__ __launch_bounds__(256) void prepro_kernel(
    const float* __restrict__ x, const float* __restrict__ w_qkv,
    const float* __restrict__ w_proj, ushort* __restrict__ xb,
    ushort* __restrict__ wqt, ushort* __restrict__ wpt, float2* __restrict__ rtab) {
  const int bid = blockIdx.x;
  const int tid = threadIdx.x;
  if (bid < 8192) {
    // x fp32 -> bf16, float4/ushort4 (n4 = 4096*2048/4 = 2097152 = 8192*256)
    int i = bid * 256 + tid;
    float4 v = ((const float4*)x)[i];
    ushort4 o;
    o.x = f2bf(v.x); o.y = f2bf(v.y); o.z = f2bf(v.z); o.w = f2bf(v.w);
    ((ushort4*)xb)[i] = o;
  } else if (bid < 8704) {
    // RoPE cos/sin table [2048][64]
    int idx = (bid - 8192) * 256 + tid;
    int i = idx & 63, l = idx >> 6;
    float inv = __builtin_amdgcn_exp2f(-(float)i * (13.287712379549449f / 64.0f));
    float f = (float)l * inv;
    float s, c;
    sincosf(f, &s, &c);
    rtab[idx] = make_float2(c, s);
  } else {
    // fp32 [R][C] -> bf16 [C][R]: w_qkv (12288 tiles) then w_proj (4096 tiles)
    const float* in;
    ushort* out;
    int R, C, bx, by;
    if (bid < 8704 + 12288) {
      int tb = bid - 8704;
      in = w_qkv; out = wqt; R = 2048; C = 6144; bx = tb % 192; by = tb / 192;
    } else {
      int tb = bid - 20992;
      in = w_proj; out = wpt; R = 2048; C = 2048; bx = tb % 64; by = tb / 64;
    }
    __shared__ ushort tile[32][33];
    int c0 = bx * 32, r0 = by * 32;
    int tx = tid & 31, ty = tid >> 5;  // 32 x 8
    for (int j = 0; j < 32; j += 8)
      tile[ty + j][tx] = f2bf(in[(size_t)(r0 + ty + j) * C + c0 + tx]);
    __syncthreads();
    int u = tid & 15;
#pragma unroll
    for (int jj = 0; jj < 2; ++jj) {
      int rowc = (tid >> 4) + jj * 16;  // output row index within tile (= input col)
      ushort2 o2;
      o2.x = tile[2 * u][rowc];
      o2.y = tile[2 * u + 1][rowc];
      *(ushort2*)(out + (size_t)(c0 + rowc) * R + r0 + 2 * u) = o2;
    }
  }
}

// ---------------- QKV GEMM: 256x256 tile, BK=64, 8 waves, 8-phase (unchanged R11) ---------
__global__ __launch_bounds__(512, 2) void gemm_qkv_kernel(
    const ushort* __restrict__ A, const ushort* __restrict__ Bt,
    ushort* __restrict__ qr, ushort* __restrict__ kr, ushort* __restrict__ vt,
    const float2* __restrict__ rtab, int K, int N) {
  __shared__ __align__(16) ushort smem[65536];  // 128 KiB: [buf][A 16384 | B 16384]
  const int tid = threadIdx.x;
  const int wave = tid >> 6, lane = tid & 63;
  const int wm = wave >> 2, wn = wave & 3;  // 2 (M) x 4 (N) waves; wave tile 128x64
  const int m0 = blockIdx.y * 256, n0 = blockIdx.x * 256;
  const int frl = lane & 15, fq = lane >> 4;
  const int sx = fq ^ (frl & 7);   // ds_read phys slot base (kk adds ^ (kk<<2))
  const int srow = tid >> 3;       // staging row 0..63 within half-tile (j adds 64)
  const int slog8 = (((tid & 7) ^ ((tid >> 3) & 7)) << 3);  // pre-swizzled global col

  const ushort* aG = A + (size_t)(m0 + srow) * K + slog8;
  const ushort* bG = Bt + (size_t)(n0 + srow) * K + slog8;
  ushort* lw = smem + wave * 512;  // wave-uniform LDS staging base

  f32x4 acc[8][4] = {};
  short8 aF[4][2], bF[2][2][2];

  auto stA = [&](int tt, int h) {
    ushort* l = lw + (tt & 1) * 32768 + h * 8192;
    const ushort* g = aG + (size_t)(h * 128) * K + tt * 64;
    async_cp16(g, l);
    async_cp16(g + (size_t)64 * K, l + 4096);
  };
  auto stB = [&](int tt, int h) {
    ushort* l = lw + (tt & 1) * 32768 + 16384 + h * 8192;
    const ushort* g = bG + (size_t)(h * 128) * K + tt * 64;
    async_cp16(g, l);
    async_cp16(g + (size_t)64 * K, l + 4096);
  };
  auto LDA = [&](int buf, int mh) {
#pragma unroll
    for (int mf = 0; mf < 4; ++mf)
#pragma unroll
      for (int kk = 0; kk < 2; ++kk)
        aF[mf][kk] = *(const short8*)(smem + buf * 32768 +
            (wm * 128 + mh * 64 + mf * 16 + frl) * 64 + ((sx ^ (kk << 2)) << 3));
  };
  auto LDB = [&](int buf, int nh) {
#pragma unroll
    for (int j = 0; j < 2; ++j)
#pragma unroll
      for (int kk = 0; kk < 2; ++kk)
        bF[nh][j][kk] = *(const short8*)(smem + buf * 32768 + 16384 +
            (wn * 64 + nh * 32 + j * 16 + frl) * 64 + ((sx ^ (kk << 2)) << 3));
  };
  auto MFMAQ = [&](int mh, int nh) {
    __builtin_amdgcn_s_setprio(1);
#pragma unroll
    for (int mf = 0; mf < 4; ++mf)
#pragma unroll
      for (int j = 0; j < 2; ++j)
#pragma unroll
        for (int kk = 0; kk < 2; ++kk)
          acc[mh * 4 + mf][nh * 2 + j] = __builtin_amdgcn_mfma_f32_16x16x32_bf16(
              aF[mf][kk], bF[nh][j][kk], acc[mh * 4 + mf][nh * 2 + j], 0, 0, 0);
    __builtin_amdgcn_s_setprio(0);
  };

  // prologue: t0 fully, t1.B halves; wait t0 landed (4 newest = t1.B in flight)
  stB(0, 0); stB(0, 1); stA(0, 0); stA(0, 1);
  stB(1, 0); stB(1, 1);
  WAITVM(4);
  BARRIER;

  const int NT = K >> 6;  // 32 K-steps
  for (int i = 0; i < NT / 2 - 1; ++i) {
    const int t = 2 * i;
    LDA(0, 0); LDB(0, 0); stA(t + 1, 0);
    BARRIER; WAITLGKM; MFMAQ(0, 0); BARRIER;
    LDB(0, 1); stA(t + 1, 1);
    BARRIER; WAITLGKM; MFMAQ(0, 1); BARRIER;
    LDA(0, 1); stB(t + 2, 0);
    BARRIER; WAITLGKM; MFMAQ(1, 0); BARRIER;
    stB(t + 2, 1);
    BARRIER; WAITLGKM; MFMAQ(1, 1); WAITVM(4); BARRIER;
    LDA(1, 0); LDB(1, 0); stA(t + 2, 0);
    BARRIER; WAITLGKM; MFMAQ(0, 0); BARRIER;
    LDB(1, 1); stA(t + 2, 1);
    BARRIER; WAITLGKM; MFMAQ(0, 1); BARRIER;
    LDA(1, 1); stB(t + 3, 0);
    BARRIER; WAITLGKM; MFMAQ(1, 0); BARRIER;
    stB(t + 3, 1);
    BARRIER; WAITLGKM; MFMAQ(1, 1); WAITVM(4); BARRIER;
  }
  {  // peeled final iteration (t = NT-2): no t+2/t+3 issues; drain before buf1 reads
    const int t = NT - 2;
    LDA(0, 0); LDB(0, 0); stA(t + 1, 0);
    BARRIER; WAITLGKM; MFMAQ(0, 0); BARRIER;
    LDB(0, 1); stA(t + 1, 1);
    BARRIER; WAITLGKM; MFMAQ(0, 1); BARRIER;
    LDA(0, 1);
    BARRIER; WAITLGKM; MFMAQ(1, 0); BARRIER;
    BARRIER; WAITLGKM; MFMAQ(1, 1); WAITVM(0); BARRIER;
    LDA(1, 0); LDB(1, 0);
    BARRIER; WAITLGKM; MFMAQ(0, 0); BARRIER;
    LDB(1, 1);
    BARRIER; WAITLGKM; MFMAQ(0, 1); BARRIER;
    LDA(1, 1);
    BARRIER; WAITLGKM; MFMAQ(1, 0); BARRIER;
    BARRIER; WAITLGKM; MFMAQ(1, 1); BARRIER;
  }

  // ---- epilogue: per-wave 128x64 tile at (m0+wm*128, n0+wn*64) ----
  const int rq = fq * 4;
  if (n0 < 4096) {
    // q/k with FUSED RoPE: partner element dh^1 is at lane^1 (same mi,ni,r).
    ushort* dst = (n0 >= 2048) ? kr : qr;
#pragma unroll
    for (int mi = 0; mi < 8; ++mi)
#pragma unroll
      for (int ni = 0; ni < 4; ++ni) {
        int col = n0 + wn * 64 + ni * 16 + frl;
        int rem = col & 2047, h = rem >> 7, dh = rem & 127;
        int ip = dh >> 1;
        float sgn = (dh & 1) ? 1.0f : -1.0f;
#pragma unroll
        for (int r = 0; r < 4; ++r) {
          int row = m0 + wm * 128 + mi * 16 + rq + r;
          int b = row >> 11, l = row & 2047;
          float v = acc[mi][ni][r];
          float vp = __shfl_xor(v, 1);
          float2 cs2 = rtab[l * 64 + ip];
          float o = v * cs2.x + sgn * vp * cs2.y;
          dst[((size_t)((b << 4) + h) * 2048 + l) * 128 + dh] = f2bf(o);
        }
      }
  } else {
    // V: wave-private barrier-free LDS transpose of 16x64 slices (reuses staging smem)
    ushort* vtile = smem + wave * 1024;
    const int col0 = n0 + wn * 64;  // >= 4096
    const int row0 = m0 + wm * 128;
    const int b = row0 >> 11, l0 = row0 & 2047;
    const int swz = (frl & 3) << 4;
#pragma unroll
    for (int hm = 0; hm < 2; ++hm)
#pragma unroll
      for (int ni = 0; ni < 4; ++ni) {
#pragma unroll
        for (int mi = 0; mi < 4; ++mi)
#pragma unroll
          for (int r = 0; r < 4; ++r) {
            int ll = mi * 16 + rq + r;
            vtile[frl * 64 + (ll ^ swz)] = f2bf(acc[hm * 4 + mi][ni][r]);
          }
#pragma unroll
        for (int tt = 0; tt < 2; ++tt) {
          int dl = tt * 8 + (lane >> 3);
          int l8 = (lane & 7) * 8;
          int lsw = l8 ^ ((dl & 3) << 4);
          int rem = (col0 + ni * 16 + dl) & 2047;
          int h = rem >> 7, dh = rem & 127;
          *(short8*)(vt + ((size_t)((b << 4) + h) * 128 + dh) * 2048 + l0 + hm * 64 + l8) =
              *(const short8*)(vtile + dl * 64 + lsw);
        }
      }
  }
}

// ---------------- GEMM -> fp32 out (proj) v3: 128x256 tile, 2 phases/K-step -------------
// R11 diagnosis: v2's 8-MFMA phases left barrier overhead dominant (513 TF vs qkv's
// ~1020 steady). v3 merges quadrant pairs -> 16 MFMA between barrier pairs, halving
// barriers per K-step (8->4). Region/FIFO algebra: stA(t+1)@phA (buf-A last read prev
// phB), stB(t+2,both)@phB (buf-B last read phA); gate vmcnt(4) at phB end leaves
// exactly t+2's 4 B-loads in flight with t+1 fully landed.
__global__ __launch_bounds__(512, 2) void gemm_out_kernel(
    const ushort* __restrict__ A, const ushort* __restrict__ Bt,
    float* __restrict__ C, int K, int N) {
  __shared__ __align__(16) ushort smem[49152];  // 96 KiB: [buf][A 8192 | B 16384]
  const int tid = threadIdx.x;
  const int wave = tid >> 6, lane = tid & 63;
  const int wm = wave >> 2, wn = wave & 3;  // 2(M) x 4(N); wave tile 64x64
  const int m0 = blockIdx.y * 128, n0 = blockIdx.x * 256;
  const int frl = lane & 15, fq = lane >> 4;
  const int sx = fq ^ (frl & 7);
  const int srow = tid >> 3;
  const int slog8 = (((tid & 7) ^ ((tid >> 3) & 7)) << 3);

  const ushort* aG = A + (size_t)(m0 + srow) * K + slog8;
  const ushort* bG = Bt + (size_t)(n0 + srow) * K + slog8;
  ushort* lw = smem + wave * 512;

  f32x4 acc[4][4] = {};
  short8 aF[2][2], bF[2][2][2];

  auto stA = [&](int tt) {  // A rows 0..127 (2 loads)
    ushort* l = lw + (tt & 1) * 24576;
    const ushort* g = aG + tt * 64;
    async_cp16(g, l);
    async_cp16(g + (size_t)64 * K, l + 4096);
  };
  auto stB = [&](int tt, int h) {  // B rows h*128..h*128+127 (2 loads)
    ushort* l = lw + (tt & 1) * 24576 + 8192 + h * 8192;
    const ushort* g = bG + (size_t)(h * 128) * K + tt * 64;
    async_cp16(g, l);
    async_cp16(g + (size_t)64 * K, l + 4096);
  };
  auto LDA = [&](int buf, int mh) {
#pragma unroll
    for (int mf = 0; mf < 2; ++mf)
#pragma unroll
      for (int kk = 0; kk < 2; ++kk)
        aF[mf][kk] = *(const short8*)(smem + buf * 24576 +
            (wm * 64 + mh * 32 + mf * 16 + frl) * 64 + ((sx ^ (kk << 2)) << 3));
  };
  auto LDB = [&](int buf, int nh) {
#pragma unroll
    for (int j = 0; j < 2; ++j)
#pragma unroll
      for (int kk = 0; kk < 2; ++kk)
        bF[nh][j][kk] = *(const short8*)(smem + buf * 24576 + 8192 +
            (wn * 64 + nh * 32 + j * 16 + frl) * 64 + ((sx ^ (kk << 2)) << 3));
  };
  auto MFMAH = [&](int mh) {  // 16 MFMA: both nh halves for one mh
    __builtin_amdgcn_s_setprio(1);
#pragma unroll
    for (int mf = 0; mf < 2; ++mf)
#pragma unroll
      for (int nh = 0; nh < 2; ++nh)
#pragma unroll
        for (int j = 0; j < 2; ++j)
#pragma unroll
          for (int kk = 0; kk < 2; ++kk)
            acc[mh * 2 + mf][nh * 2 + j] = __builtin_amdgcn_mfma_f32_16x16x32_bf16(
                aF[mf][kk], bF[nh][j][kk], acc[mh * 2 + mf][nh * 2 + j], 0, 0, 0);
    __builtin_amdgcn_s_setprio(0);
  };

  // prologue: t0 fully (6), t1's B (4); vmcnt(4) -> t0 landed, t1.B in flight
  stB(0, 0); stB(0, 1); stA(0);
  stB(1, 0); stB(1, 1);
  WAITVM(4);
  BARRIER;

  const int NT = K >> 6;  // 32 K-steps
  for (int i = 0; i < NT / 2 - 1; ++i) {
    const int t = 2 * i;
    // step t (buf0)
    LDA(0, 0); LDB(0, 0); LDB(0, 1); stA(t + 1);
    BARRIER; WAITLGKM; MFMAH(0); BARRIER;
    LDA(0, 1); stB(t + 2, 0); stB(t + 2, 1);
    BARRIER; WAITLGKM; MFMAH(1); WAITVM(4); BARRIER;
    // step t+1 (buf1)
    LDA(1, 0); LDB(1, 0); LDB(1, 1); stA(t + 2);
    BARRIER; WAITLGKM; MFMAH(0); BARRIER;
    LDA(1, 1); stB(t + 3, 0); stB(t + 3, 1);
    BARRIER; WAITLGKM; MFMAH(1); WAITVM(4); BARRIER;
  }
  {  // peeled final iteration (t = NT-2)
    const int t = NT - 2;
    LDA(0, 0); LDB(0, 0); LDB(0, 1); stA(t + 1);
    BARRIER; WAITLGKM; MFMAH(0); BARRIER;
    LDA(0, 1);
    BARRIER; WAITLGKM; MFMAH(1); WAITVM(0); BARRIER;
    LDA(1, 0); LDB(1, 0); LDB(1, 1);
    BARRIER; WAITLGKM; MFMAH(0); BARRIER;
    LDA(1, 1);
    BARRIER; WAITLGKM; MFMAH(1); BARRIER;
  }

  // ---- epilogue: plain fp32 C write; wave tile 64x64 at (m0+wm*64, n0+wn*64) ----
  const int rq = fq * 4;
#pragma unroll
  for (int mi = 0; mi < 4; ++mi)
#pragma unroll
    for (int nj = 0; nj < 4; ++nj) {
      int col = n0 + wn * 64 + nj * 16 + frl;
#pragma unroll
      for (int r = 0; r < 4; ++r) {
        int row = m0 + wm * 64 + mi * 16 + rq + r;
        C[(size_t)row * N + col] = acc[mi][nj][r];
      }
    }
}

// ---------------- Flash attention v7.1 (unchanged R11): 32x32x16, shfl P-exchange ---------
__global__ __launch_bounds__(512, 2) void flash_kernel(
    const ushort* __restrict__ qr, const ushort* __restrict__ kr,
    const ushort* __restrict__ vtg, ushort* __restrict__ att) {
  __shared__ __align__(16) ushort KV[2][16384];  // [buf][ K 64x128 | V^T 128x64 ]

  const int tid = threadIdx.x;
  const int wave = tid >> 6, lane = tid & 63;
  const int bid = blockIdx.x;
  const int swzb = (bid & 7) * 32 + (bid >> 3);  // XCD-bijective (grid 256 = 8*32)
  const int qt = swzb & 7;
  const int bh = swzb >> 3;
  const int q0 = qt * 256 + wave * 32;
  const size_t bh_base = (size_t)bh * 2048 * 128;

  const int qi = lane & 31, hi = lane >> 5;
  const float cs = 0.08838834764831845f * 1.4426950408889634f;  // scale*log2(e)
  const int rsw = (qi & 7) << 3;  // read-side XOR swizzle (row&7 == qi&7 for all reads)

  const int krow0 = wave * 8 + (lane >> 4);
  const int kgc = (lane & 15) * 8;
  const int vrow0 = wave * 16 + (lane >> 3);
  const int vgc = (lane & 7) * 8;

  auto stage = [&](int kt, int buf) {
#pragma unroll
    for (int i = 0; i < 2; ++i) {
      const int krow = krow0 + i * 4;
      async_cp16(kr + bh_base + (size_t)(kt * 64 + krow) * 128 + (kgc ^ ((krow & 7) << 3)),
                 &KV[buf][(wave * 2 + i) * 512]);
      const int vrow = vrow0 + i * 8;
      async_cp16(vtg + bh_base + (size_t)vrow * 2048 + kt * 64 + (vgc ^ ((vrow & 7) << 3)),
                 &KV[buf][8192 + (wave * 2 + i) * 512]);
    }
  };

  short8 qf[8];
  {
    const ushort* qp = qr + bh_base + (size_t)(q0 + qi) * 128 + hi * 8;
#pragma unroll
    for (int c = 0; c < 8; ++c) qf[c] = *(const short8*)(qp + c * 16);
  }

  f32x16 oacc[4];
#pragma unroll
  for (int nt = 0; nt < 4; ++nt)
#pragma unroll
    for (int r = 0; r < 16; ++r) oacc[nt][r] = 0.f;
  float l_lane = 0.f;

  stage(0, 0);
  stage(1, 1);
  WAITVM(4);
  BARRIER;

#pragma unroll 2
  for (int kt = 0; kt < 32; ++kt) {
    const int bo = (kt & 1) * 16384;
    const ushort* kv = &KV[0][0];

    f32x16 s0, s1;
#pragma unroll
    for (int r = 0; r < 16; ++r) { s0[r] = 0.f; s1[r] = 0.f; }
    const ushort* kp0 = kv + bo + (size_t)(0 * 32 + qi) * 128;
    const ushort* kp1 = kv + bo + (size_t)(1 * 32 + qi) * 128;
    __builtin_amdgcn_s_setprio(1);
#pragma unroll
    for (int c = 0; c < 8; ++c) {
      const int co = (c * 16 + hi * 8) ^ rsw;
      short8 kf0 = *(const short8*)(kp0 + co);
      short8 kf1 = *(const short8*)(kp1 + co);
      s0 = __builtin_amdgcn_mfma_f32_32x32x16_bf16(kf0, qf[c], s0, 0, 0, 0);
      s1 = __builtin_amdgcn_mfma_f32_32x32x16_bf16(kf1, qf[c], s1, 0, 0, 0);
    }
    __builtin_amdgcn_s_setprio(0);

    int pk[2][8];
#pragma unroll
    for (int m = 0; m < 8; ++m) {
      float a0 = __builtin_amdgcn_exp2f(s0[2 * m] * cs);
      float a1 = __builtin_amdgcn_exp2f(s0[2 * m + 1] * cs);
      float b0 = __builtin_amdgcn_exp2f(s1[2 * m] * cs);
      float b1 = __builtin_amdgcn_exp2f(s1[2 * m + 1] * cs);
      l_lane += (a0 + a1) + (b0 + b1);
      pk[0][m] = (int)f2bf(a0) | ((int)f2bf(a1) << 16);
      pk[1][m] = (int)f2bf(b0) | ((int)f2bf(b1) << 16);
    }

    __builtin_amdgcn_s_setprio(1);
#pragma unroll
    for (int ks = 0; ks < 4; ++ks) {
      const int kb = ks >> 1, s2 = ks & 1;
      const int a0 = pk[kb][4 * s2 + 0], a1 = pk[kb][4 * s2 + 1];
      const int a2 = pk[kb][4 * s2 + 2], a3 = pk[kb][4 * s2 + 3];
      const int p0 = __shfl_xor(a0, 32), p1 = __shfl_xor(a1, 32);
      const int p2 = __shfl_xor(a2, 32), p3 = __shfl_xor(a3, 32);
      i32x4 w;
      w[0] = hi ? p2 : a0;
      w[1] = hi ? p3 : a1;
      w[2] = hi ? a2 : p0;
      w[3] = hi ? a3 : p1;
      short8 pa = __builtin_bit_cast(short8, w);
      const int vco = (ks * 16 + hi * 8) ^ rsw;
#pragma unroll
      for (int nt = 0; nt < 4; ++nt) {
        short8 vf = *(const short8*)(kv + bo + 8192 + (size_t)(nt * 32 + qi) * 64 + vco);
        oacc[nt] = __builtin_amdgcn_mfma_f32_32x32x16_bf16(pa, vf, oacc[nt], 0, 0, 0);
      }
    }
    __builtin_amdgcn_s_setprio(0);

    BARRIER;
    if (kt < 30) {
      stage(kt + 2, kt & 1);
      WAITVM(4);
    } else {
      WAITVM(0);
    }
    BARRIER;
  }

  l_lane += __shfl_xor(l_lane, 32);
  const float linv = 1.0f / l_lane;
  const int b = bh >> 4, h = bh & 15;
#pragma unroll
  for (int r = 0; r < 16; ++r) {
    const int crow = (r & 3) + 8 * (r >> 2) + 4 * hi;
    const float inv = __shfl(linv, crow);
    const size_t rowa = (size_t)(b * 2048 + q0 + crow) * 2048 + h * 128;
#pragma unroll
    for (int nt = 0; nt < 4; ++nt)
      att[rowa + nt * 32 + qi] = f2bf(oacc[nt][r] * inv);
  }
}

extern "C" void kernel_launch(void* const* d_in, const int* in_sizes, int n_in,
                              void* d_out, int out_size, void* d_ws, size_t ws_size,
                              hipStream_t stream) {
  const float* x = (const float*)d_in[0];       // [2,2048,2048]
  const float* w_qkv = (const float*)d_in[1];   // [2048,6144]
  const float* w_proj = (const float*)d_in[2];  // [2048,2048]
  float* out = (float*)d_out;                   // [2,2048,2048] fp32

  char* p = (char*)d_ws;
  ushort* xb = (ushort*)p;  p += (size_t)4096 * 2048 * 2;
  ushort* wqt = (ushort*)p; p += (size_t)6144 * 2048 * 2;
  ushort* wpt = (ushort*)p; p += (size_t)2048 * 2048 * 2;
  ushort* qr = (ushort*)p;  p += (size_t)32 * 2048 * 128 * 2;
  ushort* kr = (ushort*)p;  p += (size_t)32 * 2048 * 128 * 2;
  ushort* vt = (ushort*)p;  p += (size_t)32 * 2048 * 128 * 2;  // [bh][128][2048]
  ushort* att = (ushort*)p; p += (size_t)4096 * 2048 * 2;
  float2* rtab = (float2*)p; p += (size_t)2048 * 64 * 8;       // 1 MB cos/sin table

  prepro_kernel<<<25088, 256, 0, stream>>>(x, w_qkv, w_proj, xb, wqt, wpt, rtab);
  gemm_qkv_kernel<<<dim3(24, 16), 512, 0, stream>>>(xb, wqt, qr, kr, vt, rtab, 2048, 6144);
  flash_kernel<<<256, 512, 0, stream>>>(qr, kr, vt, att);
  gemm_out_kernel<<<dim3(8, 32), 512, 0, stream>>>(att, wpt, out, 2048, 2048);
}